// Round 9
// baseline (156.528 us; speedup 1.0000x reference)
//
#include <hip/hip_runtime.h>

// ---------------- types ----------------
typedef __bf16 bf16;
typedef float  f32x4  __attribute__((ext_vector_type(4)));
typedef __bf16 bf16x8 __attribute__((ext_vector_type(8)));
typedef __bf16 bf16x4 __attribute__((ext_vector_type(4)));

#define GLOAD_LDS16(gsrc, ldst) \
  __builtin_amdgcn_global_load_lds((const __attribute__((address_space(1))) void*)(gsrc), \
                                   (__attribute__((address_space(3))) void*)(ldst), 16, 0, 0)

// ---------------- problem constants ----------------
constexpr int Bc   = 4;
constexpr int Tc   = 2048;
constexpr int Dc   = 512;
constexpr int Hc   = 8;
constexpr int DKc  = 64;
constexpr int DFFc = 2048;
constexpr int WINc = 128;
constexpr int Mr   = Bc * Tc;        // 8192 rows
constexpr size_t MD = (size_t)Mr * Dc;
constexpr int TVc  = 2176;           // padded t-stride of g_vT

// ---------------- device scratch (static, graph-capture safe) ----------------
__device__ bf16  g_xb[MD];                 // x cast to bf16
__device__ bf16  g_wqkvT[3 * Dc * Dc];     // [1536][512] = [wqT; wkT; wvT]
__device__ bf16  g_woT[Dc * Dc];           // [512][512]
__device__ bf16  g_w1T[DFFc * Dc];         // [2048][512]
__device__ bf16  g_w2T[Dc * DFFc];         // [512][2048]
__device__ float g_biasqkv[3 * Dc];
__device__ bf16  g_qkv[Mr * 3 * Dc];       // [8192][1536] : Q | K | (V region unused)
__device__ bf16  g_vT[(size_t)Bc * Hc * DKc * TVc];  // V^T [b][h][d][t]; t>=2048 tail stays 0
__device__ bf16  g_o[MD];                  // attention output, bf16
__device__ bf16  g_attnp[2 * MD];          // o @ wo partials (kz=0 has +bo), bf16
__device__ bf16  g_x1b[MD];                // LN1 out bf16
__device__ bf16  g_ff1[Mr * DFFc];         // relu(x1@w1+b1) bf16
__device__ bf16  g_ff2p[4 * MD];           // ff1@w2 partials (kz=0 has +b2), bf16

// ---------------- fused prep: x-cast + 6 weight transpose-casts + bias concat ----------------
// blocks [0,2048): cast x -> g_xb; [2048,3072): wq/wk/wv/wo; [3072,4096): w1;
// [4096,5120): w2; [5120,5126): bias concat.
__global__ __launch_bounds__(256) void prep_k(const float* __restrict__ x,
                                              const float* __restrict__ wq, const float* __restrict__ wk,
                                              const float* __restrict__ wv, const float* __restrict__ wo,
                                              const float* __restrict__ w1, const float* __restrict__ w2,
                                              const float* __restrict__ bq, const float* __restrict__ bk,
                                              const float* __restrict__ bv) {
  int bid = blockIdx.x;
  if (bid < 2048) {   // cast x
    size_t i = (size_t)bid * 2048 + threadIdx.x * 8;
    float4 a = *(const float4*)(x + i);
    float4 c = *(const float4*)(x + i + 4);
    bf16x8 o;
    o[0] = (bf16)a.x; o[1] = (bf16)a.y; o[2] = (bf16)a.z; o[3] = (bf16)a.w;
    o[4] = (bf16)c.x; o[5] = (bf16)c.y; o[6] = (bf16)c.z; o[7] = (bf16)c.w;
    *(bf16x8*)(g_xb + i) = o;
    return;
  }
  if (bid >= 5120) {  // bias concat
    int i = (bid - 5120) * 256 + threadIdx.x;
    if (i < 1536) g_biasqkv[i] = (i < 512) ? bq[i] : (i < 1024 ? bk[i - 512] : bv[i - 1024]);
    return;
  }
  const float* W; bf16* dst; int K, N, nx, ky;
  if (bid < 3072) {
    int local = bid - 2048;
    int wsel = local >> 8; local &= 255;
    nx = local & 15; ky = local >> 4; K = 512; N = 512;
    switch (wsel) {
      case 0: W = wq; dst = g_wqkvT;              break;
      case 1: W = wk; dst = g_wqkvT + 512 * 512;  break;
      case 2: W = wv; dst = g_wqkvT + 1024 * 512; break;
      default:W = wo; dst = g_woT;                break;
    }
  } else if (bid < 4096) {
    int local = bid - 3072;
    nx = local & 63; ky = local >> 6; K = 512; N = 2048; W = w1; dst = g_w1T;
  } else {
    int local = bid - 4096;
    nx = local & 15; ky = local >> 4; K = 2048; N = 512; W = w2; dst = g_w2T;
  }
  __shared__ float t[32][33];
  int n0 = nx * 32, k0 = ky * 32;
  int tx = threadIdx.x & 31, ty = threadIdx.x >> 5;
  #pragma unroll
  for (int i = 0; i < 4; ++i)
    t[ty + i * 8][tx] = W[(size_t)(k0 + ty + i * 8) * N + n0 + tx];
  __syncthreads();
  #pragma unroll
  for (int i = 0; i < 4; ++i)
    dst[(size_t)(n0 + ty + i * 8) * K + k0 + tx] = (bf16)t[tx][ty + i * 8];
}

// ============ 256x256 / BK=64 / 8-wave / 8-phase counted-vmcnt GEMM ============
// which: 0 = QKV (V -> g_vT transposed), 2 = FF1(relu), 3 = FF2 (split-K=4)
__global__ __launch_bounds__(512, 2) void gemm8p_k(int which, const float* __restrict__ bias_in) {
  const bf16 *A, *BT; bf16* Cb; const float* bias;
  int N, K; bool relu = false;
  int kz = blockIdx.z;
  if (which == 0)      { A = g_xb;  BT = g_wqkvT; Cb = g_qkv; bias = g_biasqkv; N = 1536; K = 512; }
  else if (which == 2) { A = g_x1b; BT = g_w1T;   Cb = g_ff1; bias = bias_in;   N = 2048; K = 512; relu = true; }
  else                 { A = g_ff1; BT = g_w2T;   Cb = g_ff2p + (size_t)kz * MD; bias = bias_in; N = 512; K = 2048; }
  if (kz) bias = nullptr;
  const int kzoff = kz * 512;
  constexpr int NT = 8;                      // 512 / BK64

  __shared__ __align__(16) bf16 lds[65536];  // 128 KiB, 2 buffers x 64 KiB

  const int tid = threadIdx.x;
  const int bm = blockIdx.x, bn = blockIdx.y;
  const int w = tid >> 6, lane = tid & 63;
  const int wm = w >> 2, wn = w & 3;         // 2M x 4N waves; per-wave 128x64
  const int r = lane & 15, gg = lane >> 4;

  const bf16* gA0 = A  + (size_t)(bm * 256) * K + kzoff;
  const bf16* gB0 = BT + (size_t)(bn * 256) * K + kzoff;

  f32x4 acc[8][4] = {};

  auto stageHalf = [&](int S) {
    if (S >= 4 * NT) return;
    const int tau = S >> 2, h = S & 3, buf = tau & 1;
    const int colT = tau * 64;
    if (h >= 2) {                            // A K-half
      const int ks = h - 2;
      char* dst = (char*)lds + buf * 65536 + ks * 16384 + w * 1024;
      #pragma unroll
      for (int swp = 0; swp < 2; ++swp) {
        int s = swp * 512 + tid;
        int row = s >> 2;
        int cb = (s & 3) ^ (((row >> 1) ^ (row >> 3)) & 3);
        GLOAD_LDS16(gA0 + (size_t)row * K + colT + ks * 32 + cb * 8, dst + swp * 8192);
      }
    } else {                                 // B M-half
      char* dst = (char*)lds + buf * 65536 + 32768 + h * 16384 + w * 1024;
      #pragma unroll
      for (int swp = 0; swp < 2; ++swp) {
        int s = swp * 512 + tid;
        int row = h * 128 + (s >> 3);
        int cb = (s & 7) ^ (row & 7);
        GLOAD_LDS16(gB0 + (size_t)row * K + colT + cb * 8, dst + swp * 8192);
      }
    }
  };

  #pragma unroll
  for (int S = 0; S < 7; ++S) stageHalf(S);
  asm volatile("s_waitcnt vmcnt(6)" ::: "memory");
  __builtin_amdgcn_s_barrier();

  #pragma unroll
  for (int t = 0; t < NT; ++t) {
    const bf16* lb = lds + (t & 1) * 32768;
    bf16x8 b0[4], b1[4], afr[4];

    // phase 0: all B frags + A(mi0-3, ks0); stage t+1 h3
    #pragma unroll
    for (int ni = 0; ni < 4; ++ni) {
      int row = wn * 64 + ni * 16 + r;
      b0[ni] = *(const bf16x8*)(lb + 16384 + row * 64 + ((gg ^ (r & 7)) << 3));
      b1[ni] = *(const bf16x8*)(lb + 16384 + row * 64 + (((4 + gg) ^ (r & 7)) << 3));
    }
    #pragma unroll
    for (int i = 0; i < 4; ++i) {
      int row = wm * 128 + i * 16 + r;
      afr[i] = *(const bf16x8*)(lb + row * 32 + ((gg ^ (((row >> 1) ^ (row >> 3)) & 3)) << 3));
    }
    asm volatile("" ::: "memory");
    stageHalf(4 * t + 7);
    __builtin_amdgcn_s_barrier();
    __builtin_amdgcn_s_setprio(1);
    #pragma unroll
    for (int i = 0; i < 4; ++i)
      #pragma unroll
      for (int ni = 0; ni < 4; ++ni)
        acc[i][ni] = __builtin_amdgcn_mfma_f32_16x16x32_bf16(afr[i], b0[ni], acc[i][ni], 0, 0, 0);
    __builtin_amdgcn_s_setprio(0);
    __builtin_amdgcn_s_barrier();

    // phase 1: A(mi4-7, ks0); stage t+2 h0
    #pragma unroll
    for (int i = 0; i < 4; ++i) {
      int row = wm * 128 + 64 + i * 16 + r;
      afr[i] = *(const bf16x8*)(lb + row * 32 + ((gg ^ (((row >> 1) ^ (row >> 3)) & 3)) << 3));
    }
    asm volatile("" ::: "memory");
    stageHalf(4 * t + 8);
    __builtin_amdgcn_s_barrier();
    __builtin_amdgcn_s_setprio(1);
    #pragma unroll
    for (int i = 0; i < 4; ++i)
      #pragma unroll
      for (int ni = 0; ni < 4; ++ni)
        acc[4 + i][ni] = __builtin_amdgcn_mfma_f32_16x16x32_bf16(afr[i], b0[ni], acc[4 + i][ni], 0, 0, 0);
    __builtin_amdgcn_s_setprio(0);
    __builtin_amdgcn_s_barrier();

    // phase 2: A(mi0-3, ks1); stage t+2 h1
    #pragma unroll
    for (int i = 0; i < 4; ++i) {
      int row = wm * 128 + i * 16 + r;
      afr[i] = *(const bf16x8*)(lb + 8192 + row * 32 + ((gg ^ (((row >> 1) ^ (row >> 3)) & 3)) << 3));
    }
    asm volatile("" ::: "memory");
    stageHalf(4 * t + 9);
    __builtin_amdgcn_s_barrier();
    __builtin_amdgcn_s_setprio(1);
    #pragma unroll
    for (int i = 0; i < 4; ++i)
      #pragma unroll
      for (int ni = 0; ni < 4; ++ni)
        acc[i][ni] = __builtin_amdgcn_mfma_f32_16x16x32_bf16(afr[i], b1[ni], acc[i][ni], 0, 0, 0);
    __builtin_amdgcn_s_setprio(0);
    __builtin_amdgcn_s_barrier();

    // phase 3: A(mi4-7, ks1); stage t+2 h2; GATE
    #pragma unroll
    for (int i = 0; i < 4; ++i) {
      int row = wm * 128 + 64 + i * 16 + r;
      afr[i] = *(const bf16x8*)(lb + 8192 + row * 32 + ((gg ^ (((row >> 1) ^ (row >> 3)) & 3)) << 3));
    }
    asm volatile("" ::: "memory");
    stageHalf(4 * t + 10);
    if (t < NT - 2)       asm volatile("s_waitcnt vmcnt(6)" ::: "memory");
    else if (t == NT - 2) asm volatile("s_waitcnt vmcnt(0)" ::: "memory");
    __builtin_amdgcn_s_barrier();
    __builtin_amdgcn_s_setprio(1);
    #pragma unroll
    for (int i = 0; i < 4; ++i)
      #pragma unroll
      for (int ni = 0; ni < 4; ++ni)
        acc[4 + i][ni] = __builtin_amdgcn_mfma_f32_16x16x32_bf16(afr[i], b1[ni], acc[4 + i][ni], 0, 0, 0);
    __builtin_amdgcn_s_setprio(0);
    __builtin_amdgcn_s_barrier();
  }

  // epilogue
  if (which == 0 && bn >= 4) {
    #pragma unroll
    for (int mi = 0; mi < 8; ++mi) {
      int row0 = bm * 256 + wm * 128 + mi * 16 + gg * 4;
      int bidx = row0 >> 11, t0 = row0 & 2047;
      #pragma unroll
      for (int ni = 0; ni < 4; ++ni) {
        int col = bn * 256 + wn * 64 + ni * 16 + r;   // in [1024,1536)
        float bv = bias[col];
        int vcol = col - 1024;
        bf16x4 ov;
        #pragma unroll
        for (int j = 0; j < 4; ++j) ov[j] = (bf16)(acc[mi][ni][j] + bv);
        *(bf16x4*)(g_vT + (size_t)(bidx * 512 + vcol) * TVc + t0) = ov;
      }
    }
    return;
  }
  #pragma unroll
  for (int mi = 0; mi < 8; ++mi) {
    int row0 = bm * 256 + wm * 128 + mi * 16 + gg * 4;
    #pragma unroll
    for (int ni = 0; ni < 4; ++ni) {
      int col = bn * 256 + wn * 64 + ni * 16 + r;
      float bv = bias ? bias[col] : 0.f;
      #pragma unroll
      for (int j = 0; j < 4; ++j) {
        float v0 = acc[mi][ni][j] + bv;
        if (relu) v0 = fmaxf(v0, 0.f);
        Cb[(size_t)(row0 + j) * N + col] = (bf16)v0;
      }
    }
  }
}

// ---------------- legacy 128x128 GEMM (O-proj only) ----------------
__global__ __launch_bounds__(256) void gemm_k(const float* __restrict__ bias_in) {
  const bf16 *A, *BT;
  bf16* Cb;
  const float* bias;
  int N, K, Klen;
  int kz = blockIdx.z;
  { A = g_o; BT = g_woT; Cb = g_attnp + (size_t)kz * MD; bias = bias_in; N = 512; K = 512; Klen = 256; }
  if (kz) bias = nullptr;

  __shared__ __align__(16) bf16 lA[128 * 32];
  __shared__ __align__(16) bf16 lB[128 * 32];
  int tid = threadIdx.x;
  int bm = blockIdx.x, bn = blockIdx.y;
  int w = tid >> 6, lane = tid & 63;
  int wm = w >> 1, wn = w & 1;
  int r = lane & 15, gg = lane >> 4;

  f32x4 acc[4][4] = {};

  const bf16* gA = A + (size_t)(bm * 128 + (tid >> 2)) * K + (size_t)kz * Klen + (tid & 3) * 8;
  const bf16* gB = BT + (size_t)(bn * 128 + (tid >> 2)) * K + (size_t)kz * Klen + (tid & 3) * 8;
  char* lAb = (char*)lA + (tid & 0xC0) * 16;
  char* lBb = (char*)lB + (tid & 0xC0) * 16;

  for (int k0 = 0; k0 < Klen; k0 += 32) {
    GLOAD_LDS16(gA + k0,                  lAb);
    GLOAD_LDS16(gA + (size_t)64 * K + k0, lAb + 4096);
    GLOAD_LDS16(gB + k0,                  lBb);
    GLOAD_LDS16(gB + (size_t)64 * K + k0, lBb + 4096);
    asm volatile("s_waitcnt vmcnt(0)" ::: "memory");
    __syncthreads();
    bf16x8 afrag[4], bfrag[4];
    #pragma unroll
    for (int i = 0; i < 4; ++i)
      afrag[i] = *(const bf16x8*)(&lA[(wm * 64 + i * 16 + r) * 32 + gg * 8]);
    #pragma unroll
    for (int i = 0; i < 4; ++i)
      bfrag[i] = *(const bf16x8*)(&lB[(wn * 64 + i * 16 + r) * 32 + gg * 8]);
    #pragma unroll
    for (int mi = 0; mi < 4; ++mi)
      #pragma unroll
      for (int ni = 0; ni < 4; ++ni)
        acc[mi][ni] = __builtin_amdgcn_mfma_f32_16x16x32_bf16(afrag[mi], bfrag[ni], acc[mi][ni], 0, 0, 0);
    __syncthreads();
  }

  #pragma unroll
  for (int mi = 0; mi < 4; ++mi) {
    int row0 = bm * 128 + wm * 64 + mi * 16 + gg * 4;
    #pragma unroll
    for (int ni = 0; ni < 4; ++ni) {
      int col = bn * 128 + wn * 64 + ni * 16 + r;
      float bv = bias ? bias[col] : 0.f;
      #pragma unroll
      for (int j = 0; j < 4; ++j) {
        float v0 = acc[mi][ni][j] + bv;
        Cb[(size_t)(row0 + j) * N + col] = (bf16)v0;
      }
    }
  }
}

// ---------------- windowed attention: barrier-free, no K/V staging ----------------
// grid (T/64, B*H), 4 waves. Each wave independently: QK^T (K direct from
// global, L1/L2-hit), softmax, P -> own 16 LDS rows (intra-wave only), PV
// (V^T direct from global). Zero workgroup barriers; 24 KB LDS.
__global__ __launch_bounds__(256) void attn_k() {
  constexpr int KT = 192;
  __shared__ __align__(16) bf16 lP[64 * KT];   // 24 KiB, rows 16w..16w+15 owned by wave w
  int tid = threadIdx.x;
  int qt = blockIdx.x, bh = blockIdx.y;
  int b = bh >> 3, h = bh & 7;
  int q0 = qt * 64;
  int w = tid >> 6, lane = tid & 63;
  int r = lane & 15, gg = lane >> 4;

  // Q fragments
  bf16x8 qf0, qf1;
  {
    int qrow = q0 + w * 16 + r;
    const bf16* qp = g_qkv + (size_t)(b * Tc + qrow) * 1536 + h * 64;
    qf0 = *(const bf16x8*)(qp + gg * 8);
    qf1 = *(const bf16x8*)(qp + 32 + gg * 8);
  }

  // S = Q K^T, K rows direct from global
  const bf16* kbase = g_qkv + (size_t)b * Tc * 1536 + 512 + h * 64;
  f32x4 s[12] = {};
  #pragma unroll
  for (int ni = 0; ni < 12; ++ni) {
    int gkey = q0 + ni * 16 + r;
    const bf16* kp = kbase + (size_t)(gkey < Tc ? gkey : 0) * 1536;
    bf16x8 k0f = *(const bf16x8*)(kp + gg * 8);
    bf16x8 k1f = *(const bf16x8*)(kp + 32 + gg * 8);
    s[ni] = __builtin_amdgcn_mfma_f32_16x16x32_bf16(qf0, k0f, s[ni], 0, 0, 0);
    s[ni] = __builtin_amdgcn_mfma_f32_16x16x32_bf16(qf1, k1f, s[ni], 0, 0, 0);
  }

  // mask (k in [q, q+WIN), k < T) + softmax over 16-lane groups
  float mx[4] = {-3e38f, -3e38f, -3e38f, -3e38f};
  #pragma unroll
  for (int ni = 0; ni < 12; ++ni)
    #pragma unroll
    for (int j = 0; j < 4; ++j) {
      int qloc = w * 16 + gg * 4 + j;
      int col = ni * 16 + r;
      bool valid = (col >= qloc) && (col < qloc + WINc) && (q0 + col < Tc);
      float sv = valid ? s[ni][j] * 0.125f : -3e38f;
      s[ni][j] = sv;
      mx[j] = fmaxf(mx[j], sv);
    }
  #pragma unroll
  for (int m = 1; m < 16; m <<= 1)
    #pragma unroll
    for (int j = 0; j < 4; ++j) mx[j] = fmaxf(mx[j], __shfl_xor(mx[j], m, 64));

  float sm[4] = {0.f, 0.f, 0.f, 0.f};
  #pragma unroll
  for (int ni = 0; ni < 12; ++ni)
    #pragma unroll
    for (int j = 0; j < 4; ++j) {
      float p = __expf(s[ni][j] - mx[j]);
      s[ni][j] = p;
      sm[j] += p;
    }
  #pragma unroll
  for (int m = 1; m < 16; m <<= 1)
    #pragma unroll
    for (int j = 0; j < 4; ++j) sm[j] += __shfl_xor(sm[j], m, 64);

  // write P (unnormalized bf16) into this wave's own LDS rows, chunk ^ (q&7)
  #pragma unroll
  for (int ni = 0; ni < 12; ++ni)
    #pragma unroll
    for (int j = 0; j < 4; ++j) {
      int q = w * 16 + gg * 4 + j;
      int col = ni * 16 + r;
      int idx = q * KT + ((((col >> 3) ^ (q & 7)) << 3) | (col & 7));
      lP[idx] = (bf16)s[ni][j];
    }
  // intra-wave LDS write->read ordering only (no cross-wave sharing)
  asm volatile("s_waitcnt lgkmcnt(0)" ::: "memory");
  __builtin_amdgcn_sched_barrier(0);

  // O = P V : pf from own LDS rows, vf direct from g_vT
  const bf16* vb = g_vT + (size_t)(bh * 64) * TVc;
  f32x4 o[4] = {};
  int swl = r & 7;
  #pragma unroll
  for (int ks = 0; ks < 6; ++ks) {
    int ch = ((ks * 4 + gg) ^ swl) << 3;
    bf16x8 pf = *(const bf16x8*)(&lP[(w * 16 + r) * KT + ch]);
    int t = q0 + ks * 32 + gg * 8;
    int tok = (t < Tc) ? t : 0;     // invalid chunks: P=0, read finite col 0
    #pragma unroll
    for (int nf = 0; nf < 4; ++nf) {
      bf16x8 vf = *(const bf16x8*)(vb + (size_t)(nf * 16 + r) * TVc + tok);
      o[nf] = __builtin_amdgcn_mfma_f32_16x16x32_bf16(pf, vf, o[nf], 0, 0, 0);
    }
  }
  #pragma unroll
  for (int nf = 0; nf < 4; ++nf) {
    int dk = nf * 16 + r;
    #pragma unroll
    for (int j = 0; j < 4; ++j) {
      int qloc = w * 16 + gg * 4 + j;
      float ov = o[nf][j] / sm[j];
      g_o[(size_t)(b * Tc + q0 + qloc) * Dc + h * 64 + dk] = (bf16)ov;
    }
  }
}

// ---------------- residual (bf16 base + np bf16 partials) + LayerNorm ----------------
__global__ __launch_bounds__(256) void ln_k(int which, const float* __restrict__ gw,
                                            const float* __restrict__ bw,
                                            float* __restrict__ outf_in) {
  int row = blockIdx.x * 4 + (threadIdx.x >> 6);
  int lane = threadIdx.x & 63;
  const bf16* a; const bf16* pb; int np; float* outf; bf16* outb;
  if (which == 0) { a = g_xb;  pb = g_attnp; np = 2; outf = nullptr;  outb = g_x1b; }
  else            { a = g_x1b; pb = g_ff2p;  np = 4; outf = outf_in;  outb = nullptr; }
  size_t off = (size_t)row * 512 + lane * 8;
  bf16x8 av = *(const bf16x8*)(a + off);
  float v[8];
  #pragma unroll
  for (int i = 0; i < 8; ++i) v[i] = (float)av[i];
  for (int p = 0; p < np; ++p) {
    bf16x8 t = *(const bf16x8*)(pb + (size_t)p * MD + off);
    #pragma unroll
    for (int i = 0; i < 8; ++i) v[i] += (float)t[i];
  }
  float s = 0.f;
  #pragma unroll
  for (int i = 0; i < 8; ++i) s += v[i];
  #pragma unroll
  for (int m = 1; m < 64; m <<= 1) s += __shfl_xor(s, m, 64);
  float mean = s * (1.0f / 512.0f);
  float q = 0.f;
  #pragma unroll
  for (int i = 0; i < 8; ++i) { float d = v[i] - mean; q += d * d; }
  #pragma unroll
  for (int m = 1; m < 64; m <<= 1) q += __shfl_xor(q, m, 64);
  float rstd = rsqrtf(q * (1.0f / 512.0f) + 1e-5f);
  float4 g0 = *(const float4*)(gw + lane * 8), g1v = *(const float4*)(gw + lane * 8 + 4);
  float4 e0 = *(const float4*)(bw + lane * 8), e1 = *(const float4*)(bw + lane * 8 + 4);
  float gg[8] = {g0.x, g0.y, g0.z, g0.w, g1v.x, g1v.y, g1v.z, g1v.w};
  float bb[8] = {e0.x, e0.y, e0.z, e0.w, e1.x, e1.y, e1.z, e1.w};
  float o[8];
  #pragma unroll
  for (int i = 0; i < 8; ++i) o[i] = (v[i] - mean) * rstd * gg[i] + bb[i];
  if (outf) {
    float4 o0 = {o[0], o[1], o[2], o[3]}, o1 = {o[4], o[5], o[6], o[7]};
    *(float4*)(outf + off) = o0;
    *(float4*)(outf + off + 4) = o1;
  }
  if (outb) {
    bf16x8 ob;
    #pragma unroll
    for (int i = 0; i < 8; ++i) ob[i] = (bf16)o[i];
    *(bf16x8*)(outb + off) = ob;
  }
}

// ---------------- launch ----------------
extern "C" void kernel_launch(void* const* d_in, const int* in_sizes, int n_in,
                              void* d_out, int out_size, void* d_ws, size_t ws_size,
                              hipStream_t stream) {
  const float* x   = (const float*)d_in[0];
  const float* wq  = (const float*)d_in[2];
  const float* bq  = (const float*)d_in[3];
  const float* wk  = (const float*)d_in[4];
  const float* bk  = (const float*)d_in[5];
  const float* wv  = (const float*)d_in[6];
  const float* bv  = (const float*)d_in[7];
  const float* wo  = (const float*)d_in[8];
  const float* bo  = (const float*)d_in[9];
  const float* w1  = (const float*)d_in[10];
  const float* b1  = (const float*)d_in[11];
  const float* w2  = (const float*)d_in[12];
  const float* b2  = (const float*)d_in[13];
  const float* g1  = (const float*)d_in[14];
  const float* be1 = (const float*)d_in[15];
  const float* g2  = (const float*)d_in[16];
  const float* be2 = (const float*)d_in[17];
  float* out = (float*)d_out;

  prep_k<<<5126, 256, 0, stream>>>(x, wq, wk, wv, wo, w1, w2, bq, bk, bv);

  gemm8p_k<<<dim3(32, 6, 1), 512, 0, stream>>>(0, nullptr);    // QKV (V -> g_vT)
  attn_k<<<dim3(32, 32), 256, 0, stream>>>();                  // windowed attention
  gemm_k<<<dim3(64, 4, 2), 256, 0, stream>>>(bo);              // O-proj, split-K=2
  ln_k<<<2048, 256, 0, stream>>>(0, g1, be1, nullptr);         // LN1 -> x1b
  gemm8p_k<<<dim3(32, 8, 1), 512, 0, stream>>>(2, b1);         // FF1 + relu
  gemm8p_k<<<dim3(32, 2, 4), 512, 0, stream>>>(3, b2);         // FF2, split-K=4
  ln_k<<<2048, 256, 0, stream>>>(1, g2, be2, out);             // LN2 -> out
}

// Round 10
// 145.120 us; speedup vs baseline: 1.0786x; 1.0786x over previous
//
#include <hip/hip_runtime.h>

// ---------------- types ----------------
typedef __bf16 bf16;
typedef float  f32x4  __attribute__((ext_vector_type(4)));
typedef __bf16 bf16x8 __attribute__((ext_vector_type(8)));
typedef __bf16 bf16x4 __attribute__((ext_vector_type(4)));

#define GLOAD_LDS16(gsrc, ldst) \
  __builtin_amdgcn_global_load_lds((const __attribute__((address_space(1))) void*)(gsrc), \
                                   (__attribute__((address_space(3))) void*)(ldst), 16, 0, 0)

// ---------------- problem constants ----------------
constexpr int Bc   = 4;
constexpr int Tc   = 2048;
constexpr int Dc   = 512;
constexpr int Hc   = 8;
constexpr int DKc  = 64;
constexpr int DFFc = 2048;
constexpr int WINc = 128;
constexpr int Mr   = Bc * Tc;        // 8192 rows
constexpr size_t MD = (size_t)Mr * Dc;
constexpr int TVc  = 2176;           // padded t-stride of g_vT

// ---------------- device scratch (static, graph-capture safe) ----------------
__device__ bf16  g_xb[MD];                 // x cast to bf16
__device__ bf16  g_wqkvT[3 * Dc * Dc];     // [1536][512] = [wqT; wkT; wvT]
__device__ bf16  g_woT[Dc * Dc];           // [512][512]
__device__ bf16  g_w1T[DFFc * Dc];         // [2048][512]
__device__ bf16  g_w2T[Dc * DFFc];         // [512][2048]
__device__ float g_biasqkv[3 * Dc];
__device__ bf16  g_qkv[Mr * 3 * Dc];       // [8192][1536] : Q | K | (V region unused)
__device__ bf16  g_vT[(size_t)Bc * Hc * DKc * TVc];  // V^T [b][h][d][t]; t>=2048 tail stays 0
__device__ bf16  g_o[MD];                  // attention output, bf16
__device__ bf16  g_attnp[2 * MD];          // o @ wo partials (kz=0 has +bo), bf16
__device__ bf16  g_x1b[MD];                // LN1 out bf16
__device__ bf16  g_ff1[Mr * DFFc];         // relu(x1@w1+b1) bf16
__device__ bf16  g_ff2p[4 * MD];           // ff1@w2 partials (kz=0 has +b2), bf16

// ---------------- fused prep: x-cast + 6 weight transpose-casts + bias concat ----------------
__global__ __launch_bounds__(256) void prep_k(const float* __restrict__ x,
                                              const float* __restrict__ wq, const float* __restrict__ wk,
                                              const float* __restrict__ wv, const float* __restrict__ wo,
                                              const float* __restrict__ w1, const float* __restrict__ w2,
                                              const float* __restrict__ bq, const float* __restrict__ bk,
                                              const float* __restrict__ bv) {
  int bid = blockIdx.x;
  if (bid < 2048) {   // cast x
    size_t i = (size_t)bid * 2048 + threadIdx.x * 8;
    float4 a = *(const float4*)(x + i);
    float4 c = *(const float4*)(x + i + 4);
    bf16x8 o;
    o[0] = (bf16)a.x; o[1] = (bf16)a.y; o[2] = (bf16)a.z; o[3] = (bf16)a.w;
    o[4] = (bf16)c.x; o[5] = (bf16)c.y; o[6] = (bf16)c.z; o[7] = (bf16)c.w;
    *(bf16x8*)(g_xb + i) = o;
    return;
  }
  if (bid >= 5120) {  // bias concat
    int i = (bid - 5120) * 256 + threadIdx.x;
    if (i < 1536) g_biasqkv[i] = (i < 512) ? bq[i] : (i < 1024 ? bk[i - 512] : bv[i - 1024]);
    return;
  }
  const float* W; bf16* dst; int K, N, nx, ky;
  if (bid < 3072) {
    int local = bid - 2048;
    int wsel = local >> 8; local &= 255;
    nx = local & 15; ky = local >> 4; K = 512; N = 512;
    switch (wsel) {
      case 0: W = wq; dst = g_wqkvT;              break;
      case 1: W = wk; dst = g_wqkvT + 512 * 512;  break;
      case 2: W = wv; dst = g_wqkvT + 1024 * 512; break;
      default:W = wo; dst = g_woT;                break;
    }
  } else if (bid < 4096) {
    int local = bid - 3072;
    nx = local & 63; ky = local >> 6; K = 512; N = 2048; W = w1; dst = g_w1T;
  } else {
    int local = bid - 4096;
    nx = local & 15; ky = local >> 4; K = 2048; N = 512; W = w2; dst = g_w2T;
  }
  __shared__ float t[32][33];
  int n0 = nx * 32, k0 = ky * 32;
  int tx = threadIdx.x & 31, ty = threadIdx.x >> 5;
  #pragma unroll
  for (int i = 0; i < 4; ++i)
    t[ty + i * 8][tx] = W[(size_t)(k0 + ty + i * 8) * N + n0 + tx];
  __syncthreads();
  #pragma unroll
  for (int i = 0; i < 4; ++i)
    dst[(size_t)(n0 + ty + i * 8) * K + k0 + tx] = (bf16)t[tx][ty + i * 8];
}

// ============ 256x256 / BK=64 / 8-wave / 8-phase counted-vmcnt GEMM ============
// which: 0 = QKV (V -> g_vT transposed), 2 = FF1(relu), 3 = FF2 (split-K=4)
__global__ __launch_bounds__(512, 2) void gemm8p_k(int which, const float* __restrict__ bias_in) {
  const bf16 *A, *BT; bf16* Cb; const float* bias;
  int N, K; bool relu = false;
  int kz = blockIdx.z;
  if (which == 0)      { A = g_xb;  BT = g_wqkvT; Cb = g_qkv; bias = g_biasqkv; N = 1536; K = 512; }
  else if (which == 2) { A = g_x1b; BT = g_w1T;   Cb = g_ff1; bias = bias_in;   N = 2048; K = 512; relu = true; }
  else                 { A = g_ff1; BT = g_w2T;   Cb = g_ff2p + (size_t)kz * MD; bias = bias_in; N = 512; K = 2048; }
  if (kz) bias = nullptr;
  const int kzoff = kz * 512;
  constexpr int NT = 8;                      // 512 / BK64

  __shared__ __align__(16) bf16 lds[65536];  // 128 KiB, 2 buffers x 64 KiB

  const int tid = threadIdx.x;
  const int bm = blockIdx.x, bn = blockIdx.y;
  const int w = tid >> 6, lane = tid & 63;
  const int wm = w >> 2, wn = w & 3;         // 2M x 4N waves; per-wave 128x64
  const int r = lane & 15, gg = lane >> 4;

  const bf16* gA0 = A  + (size_t)(bm * 256) * K + kzoff;
  const bf16* gB0 = BT + (size_t)(bn * 256) * K + kzoff;

  f32x4 acc[8][4] = {};

  auto stageHalf = [&](int S) {
    if (S >= 4 * NT) return;
    const int tau = S >> 2, h = S & 3, buf = tau & 1;
    const int colT = tau * 64;
    if (h >= 2) {                            // A K-half
      const int ks = h - 2;
      char* dst = (char*)lds + buf * 65536 + ks * 16384 + w * 1024;
      #pragma unroll
      for (int swp = 0; swp < 2; ++swp) {
        int s = swp * 512 + tid;
        int row = s >> 2;
        int cb = (s & 3) ^ (((row >> 1) ^ (row >> 3)) & 3);
        GLOAD_LDS16(gA0 + (size_t)row * K + colT + ks * 32 + cb * 8, dst + swp * 8192);
      }
    } else {                                 // B M-half
      char* dst = (char*)lds + buf * 65536 + 32768 + h * 16384 + w * 1024;
      #pragma unroll
      for (int swp = 0; swp < 2; ++swp) {
        int s = swp * 512 + tid;
        int row = h * 128 + (s >> 3);
        int cb = (s & 7) ^ (row & 7);
        GLOAD_LDS16(gB0 + (size_t)row * K + colT + cb * 8, dst + swp * 8192);
      }
    }
  };

  #pragma unroll
  for (int S = 0; S < 7; ++S) stageHalf(S);
  asm volatile("s_waitcnt vmcnt(6)" ::: "memory");
  __builtin_amdgcn_s_barrier();

  #pragma unroll
  for (int t = 0; t < NT; ++t) {
    const bf16* lb = lds + (t & 1) * 32768;
    bf16x8 b0[4], b1[4], afr[4];

    // phase 0: all B frags + A(mi0-3, ks0); stage t+1 h3
    #pragma unroll
    for (int ni = 0; ni < 4; ++ni) {
      int row = wn * 64 + ni * 16 + r;
      b0[ni] = *(const bf16x8*)(lb + 16384 + row * 64 + ((gg ^ (r & 7)) << 3));
      b1[ni] = *(const bf16x8*)(lb + 16384 + row * 64 + (((4 + gg) ^ (r & 7)) << 3));
    }
    #pragma unroll
    for (int i = 0; i < 4; ++i) {
      int row = wm * 128 + i * 16 + r;
      afr[i] = *(const bf16x8*)(lb + row * 32 + ((gg ^ (((row >> 1) ^ (row >> 3)) & 3)) << 3));
    }
    asm volatile("" ::: "memory");
    stageHalf(4 * t + 7);
    __builtin_amdgcn_s_barrier();
    __builtin_amdgcn_s_setprio(1);
    #pragma unroll
    for (int i = 0; i < 4; ++i)
      #pragma unroll
      for (int ni = 0; ni < 4; ++ni)
        acc[i][ni] = __builtin_amdgcn_mfma_f32_16x16x32_bf16(afr[i], b0[ni], acc[i][ni], 0, 0, 0);
    __builtin_amdgcn_s_setprio(0);
    __builtin_amdgcn_s_barrier();

    // phase 1: A(mi4-7, ks0); stage t+2 h0
    #pragma unroll
    for (int i = 0; i < 4; ++i) {
      int row = wm * 128 + 64 + i * 16 + r;
      afr[i] = *(const bf16x8*)(lb + row * 32 + ((gg ^ (((row >> 1) ^ (row >> 3)) & 3)) << 3));
    }
    asm volatile("" ::: "memory");
    stageHalf(4 * t + 8);
    __builtin_amdgcn_s_barrier();
    __builtin_amdgcn_s_setprio(1);
    #pragma unroll
    for (int i = 0; i < 4; ++i)
      #pragma unroll
      for (int ni = 0; ni < 4; ++ni)
        acc[4 + i][ni] = __builtin_amdgcn_mfma_f32_16x16x32_bf16(afr[i], b0[ni], acc[4 + i][ni], 0, 0, 0);
    __builtin_amdgcn_s_setprio(0);
    __builtin_amdgcn_s_barrier();

    // phase 2: A(mi0-3, ks1); stage t+2 h1
    #pragma unroll
    for (int i = 0; i < 4; ++i) {
      int row = wm * 128 + i * 16 + r;
      afr[i] = *(const bf16x8*)(lb + 8192 + row * 32 + ((gg ^ (((row >> 1) ^ (row >> 3)) & 3)) << 3));
    }
    asm volatile("" ::: "memory");
    stageHalf(4 * t + 9);
    __builtin_amdgcn_s_barrier();
    __builtin_amdgcn_s_setprio(1);
    #pragma unroll
    for (int i = 0; i < 4; ++i)
      #pragma unroll
      for (int ni = 0; ni < 4; ++ni)
        acc[i][ni] = __builtin_amdgcn_mfma_f32_16x16x32_bf16(afr[i], b1[ni], acc[i][ni], 0, 0, 0);
    __builtin_amdgcn_s_setprio(0);
    __builtin_amdgcn_s_barrier();

    // phase 3: A(mi4-7, ks1); stage t+2 h2; GATE
    #pragma unroll
    for (int i = 0; i < 4; ++i) {
      int row = wm * 128 + 64 + i * 16 + r;
      afr[i] = *(const bf16x8*)(lb + 8192 + row * 32 + ((gg ^ (((row >> 1) ^ (row >> 3)) & 3)) << 3));
    }
    asm volatile("" ::: "memory");
    stageHalf(4 * t + 10);
    if (t < NT - 2)       asm volatile("s_waitcnt vmcnt(6)" ::: "memory");
    else if (t == NT - 2) asm volatile("s_waitcnt vmcnt(0)" ::: "memory");
    __builtin_amdgcn_s_barrier();
    __builtin_amdgcn_s_setprio(1);
    #pragma unroll
    for (int i = 0; i < 4; ++i)
      #pragma unroll
      for (int ni = 0; ni < 4; ++ni)
        acc[4 + i][ni] = __builtin_amdgcn_mfma_f32_16x16x32_bf16(afr[i], b1[ni], acc[4 + i][ni], 0, 0, 0);
    __builtin_amdgcn_s_setprio(0);
    __builtin_amdgcn_s_barrier();
  }

  // epilogue
  if (which == 0 && bn >= 4) {
    #pragma unroll
    for (int mi = 0; mi < 8; ++mi) {
      int row0 = bm * 256 + wm * 128 + mi * 16 + gg * 4;
      int bidx = row0 >> 11, t0 = row0 & 2047;
      #pragma unroll
      for (int ni = 0; ni < 4; ++ni) {
        int col = bn * 256 + wn * 64 + ni * 16 + r;   // in [1024,1536)
        float bv = bias[col];
        int vcol = col - 1024;
        bf16x4 ov;
        #pragma unroll
        for (int j = 0; j < 4; ++j) ov[j] = (bf16)(acc[mi][ni][j] + bv);
        *(bf16x4*)(g_vT + (size_t)(bidx * 512 + vcol) * TVc + t0) = ov;
      }
    }
    return;
  }
  #pragma unroll
  for (int mi = 0; mi < 8; ++mi) {
    int row0 = bm * 256 + wm * 128 + mi * 16 + gg * 4;
    #pragma unroll
    for (int ni = 0; ni < 4; ++ni) {
      int col = bn * 256 + wn * 64 + ni * 16 + r;
      float bv = bias ? bias[col] : 0.f;
      #pragma unroll
      for (int j = 0; j < 4; ++j) {
        float v0 = acc[mi][ni][j] + bv;
        if (relu) v0 = fmaxf(v0, 0.f);
        Cb[(size_t)(row0 + j) * N + col] = (bf16)v0;
      }
    }
  }
}

// ---------------- legacy 128x128 GEMM (O-proj only) ----------------
__global__ __launch_bounds__(256) void gemm_k(const float* __restrict__ bias_in) {
  const bf16 *A, *BT;
  bf16* Cb;
  const float* bias;
  int N, K, Klen;
  int kz = blockIdx.z;
  { A = g_o; BT = g_woT; Cb = g_attnp + (size_t)kz * MD; bias = bias_in; N = 512; K = 512; Klen = 256; }
  if (kz) bias = nullptr;

  __shared__ __align__(16) bf16 lA[128 * 32];
  __shared__ __align__(16) bf16 lB[128 * 32];
  int tid = threadIdx.x;
  int bm = blockIdx.x, bn = blockIdx.y;
  int w = tid >> 6, lane = tid & 63;
  int wm = w >> 1, wn = w & 1;
  int r = lane & 15, gg = lane >> 4;

  f32x4 acc[4][4] = {};

  const bf16* gA = A + (size_t)(bm * 128 + (tid >> 2)) * K + (size_t)kz * Klen + (tid & 3) * 8;
  const bf16* gB = BT + (size_t)(bn * 128 + (tid >> 2)) * K + (size_t)kz * Klen + (tid & 3) * 8;
  char* lAb = (char*)lA + (tid & 0xC0) * 16;
  char* lBb = (char*)lB + (tid & 0xC0) * 16;

  for (int k0 = 0; k0 < Klen; k0 += 32) {
    GLOAD_LDS16(gA + k0,                  lAb);
    GLOAD_LDS16(gA + (size_t)64 * K + k0, lAb + 4096);
    GLOAD_LDS16(gB + k0,                  lBb);
    GLOAD_LDS16(gB + (size_t)64 * K + k0, lBb + 4096);
    asm volatile("s_waitcnt vmcnt(0)" ::: "memory");
    __syncthreads();
    bf16x8 afrag[4], bfrag[4];
    #pragma unroll
    for (int i = 0; i < 4; ++i)
      afrag[i] = *(const bf16x8*)(&lA[(wm * 64 + i * 16 + r) * 32 + gg * 8]);
    #pragma unroll
    for (int i = 0; i < 4; ++i)
      bfrag[i] = *(const bf16x8*)(&lB[(wn * 64 + i * 16 + r) * 32 + gg * 8]);
    #pragma unroll
    for (int mi = 0; mi < 4; ++mi)
      #pragma unroll
      for (int ni = 0; ni < 4; ++ni)
        acc[mi][ni] = __builtin_amdgcn_mfma_f32_16x16x32_bf16(afrag[mi], bfrag[ni], acc[mi][ni], 0, 0, 0);
    __syncthreads();
  }

  #pragma unroll
  for (int mi = 0; mi < 4; ++mi) {
    int row0 = bm * 128 + wm * 64 + mi * 16 + gg * 4;
    #pragma unroll
    for (int ni = 0; ni < 4; ++ni) {
      int col = bn * 128 + wn * 64 + ni * 16 + r;
      float bv = bias ? bias[col] : 0.f;
      #pragma unroll
      for (int j = 0; j < 4; ++j) {
        float v0 = acc[mi][ni][j] + bv;
        Cb[(size_t)(row0 + j) * N + col] = (bf16)v0;
      }
    }
  }
}

// ---------------- windowed attention (round-8 staged, bank-conflict-free LDS) ----------------
// grid: (T/64, B*H). Block: 4 waves, 64 queries, keys [q0, q0+192).
// K and V^T staged via global_load_lds with PRE-SWIZZLED GLOBAL source
// (linear LDS dest, rule 21); P swizzled on both write and read.
__global__ __launch_bounds__(256) void attn_k() {
  constexpr int KT = 192;
  __shared__ __align__(16) bf16 lKP[KT * 64];  // K [key][8ch swz] -> reused as P [64][24ch swz]
  __shared__ __align__(16) bf16 lVT[64 * KT];  // V^T [d][24ch swz]
  int tid = threadIdx.x;
  int qt = blockIdx.x, bh = blockIdx.y;
  int b = bh >> 3, h = bh & 7;
  int q0 = qt * 64;
  int w = tid >> 6, lane = tid & 63;
  int r = lane & 15, gg = lane >> 4;

  // stage K: slot s -> key=s>>3, stored chunk=s&7, logical chunk cb=(s&7)^(key&7)
  {
    const bf16* kbase = g_qkv + (size_t)b * Tc * 1536 + 512 + h * 64;
    char* ldst = (char*)lKP + w * 1024;
    #pragma unroll
    for (int p = 0; p < 6; ++p) {
      int s = p * 256 + tid;
      int key = s >> 3;
      int cb = (s & 7) ^ (key & 7);
      int gkey = q0 + key;
      int srow = gkey < Tc ? gkey : 0;
      GLOAD_LDS16(kbase + (size_t)srow * 1536 + cb * 8, ldst + p * 4096);
    }
  }
  // stage V^T rows from g_vT: slot s -> d=s/24, stored chunk=s%24, cb=sc^(d&7)
  {
    const bf16* vbase = g_vT + (size_t)(bh * 64) * TVc + q0;
    char* ldst = (char*)lVT + w * 1024;
    #pragma unroll
    for (int p = 0; p < 6; ++p) {
      int s = p * 256 + tid;
      int d = s / 24;
      int sc = s - d * 24;
      int cb = sc ^ (d & 7);
      GLOAD_LDS16(vbase + (size_t)d * TVc + cb * 8, ldst + p * 4096);
    }
  }
  bf16x8 qf0, qf1;
  {
    int qrow = q0 + w * 16 + r;
    const bf16* qp = g_qkv + (size_t)(b * Tc + qrow) * 1536 + h * 64;
    qf0 = *(const bf16x8*)(qp + gg * 8);
    qf1 = *(const bf16x8*)(qp + 32 + gg * 8);
  }
  asm volatile("s_waitcnt vmcnt(0)" ::: "memory");
  __syncthreads();

  f32x4 s[12] = {};
  #pragma unroll
  for (int ni = 0; ni < 12; ++ni) {
    int key = ni * 16 + r;
    int sw = key & 7;
    bf16x8 k0f = *(const bf16x8*)(&lKP[key * 64 + ((gg ^ sw) << 3)]);
    bf16x8 k1f = *(const bf16x8*)(&lKP[key * 64 + (((4 | gg) ^ sw) << 3)]);
    s[ni] = __builtin_amdgcn_mfma_f32_16x16x32_bf16(qf0, k0f, s[ni], 0, 0, 0);
    s[ni] = __builtin_amdgcn_mfma_f32_16x16x32_bf16(qf1, k1f, s[ni], 0, 0, 0);
  }

  float mx[4] = {-3e38f, -3e38f, -3e38f, -3e38f};
  #pragma unroll
  for (int ni = 0; ni < 12; ++ni)
    #pragma unroll
    for (int j = 0; j < 4; ++j) {
      int qloc = w * 16 + gg * 4 + j;
      int col = ni * 16 + r;
      bool valid = (col >= qloc) && (col < qloc + WINc) && (q0 + col < Tc);
      float sv = valid ? s[ni][j] * 0.125f : -3e38f;
      s[ni][j] = sv;
      mx[j] = fmaxf(mx[j], sv);
    }
  #pragma unroll
  for (int m = 1; m < 16; m <<= 1)
    #pragma unroll
    for (int j = 0; j < 4; ++j) mx[j] = fmaxf(mx[j], __shfl_xor(mx[j], m, 64));

  float sm[4] = {0.f, 0.f, 0.f, 0.f};
  #pragma unroll
  for (int ni = 0; ni < 12; ++ni)
    #pragma unroll
    for (int j = 0; j < 4; ++j) {
      float p = __expf(s[ni][j] - mx[j]);
      s[ni][j] = p;
      sm[j] += p;
    }
  #pragma unroll
  for (int m = 1; m < 16; m <<= 1)
    #pragma unroll
    for (int j = 0; j < 4; ++j) sm[j] += __shfl_xor(sm[j], m, 64);

  __syncthreads();
  #pragma unroll
  for (int ni = 0; ni < 12; ++ni)
    #pragma unroll
    for (int j = 0; j < 4; ++j) {
      int q = w * 16 + gg * 4 + j;
      int col = ni * 16 + r;
      int idx = q * KT + ((((col >> 3) ^ (q & 7)) << 3) | (col & 7));
      lKP[idx] = (bf16)s[ni][j];
    }
  __syncthreads();

  f32x4 o[4] = {};
  int swl = r & 7;
  #pragma unroll
  for (int ks = 0; ks < 6; ++ks) {
    int ch = ((ks * 4 + gg) ^ swl) << 3;
    bf16x8 pf = *(const bf16x8*)(&lKP[(w * 16 + r) * KT + ch]);
    #pragma unroll
    for (int nf = 0; nf < 4; ++nf) {
      bf16x8 vf = *(const bf16x8*)(&lVT[(nf * 16 + r) * KT + ch]);
      o[nf] = __builtin_amdgcn_mfma_f32_16x16x32_bf16(pf, vf, o[nf], 0, 0, 0);
    }
  }
  #pragma unroll
  for (int nf = 0; nf < 4; ++nf) {
    int dk = nf * 16 + r;
    #pragma unroll
    for (int j = 0; j < 4; ++j) {
      int qloc = w * 16 + gg * 4 + j;
      float ov = o[nf][j] / sm[j];
      g_o[(size_t)(b * Tc + q0 + qloc) * Dc + h * 64 + dk] = (bf16)ov;
    }
  }
}

// ---------------- residual (bf16 base + np bf16 partials) + LayerNorm ----------------
__global__ __launch_bounds__(256) void ln_k(int which, const float* __restrict__ gw,
                                            const float* __restrict__ bw,
                                            float* __restrict__ outf_in) {
  int row = blockIdx.x * 4 + (threadIdx.x >> 6);
  int lane = threadIdx.x & 63;
  const bf16* a; const bf16* pb; int np; float* outf; bf16* outb;
  if (which == 0) { a = g_xb;  pb = g_attnp; np = 2; outf = nullptr;  outb = g_x1b; }
  else            { a = g_x1b; pb = g_ff2p;  np = 4; outf = outf_in;  outb = nullptr; }
  size_t off = (size_t)row * 512 + lane * 8;
  bf16x8 av = *(const bf16x8*)(a + off);
  float v[8];
  #pragma unroll
  for (int i = 0; i < 8; ++i) v[i] = (float)av[i];
  for (int p = 0; p < np; ++p) {
    bf16x8 t = *(const bf16x8*)(pb + (size_t)p * MD + off);
    #pragma unroll
    for (int i = 0; i < 8; ++i) v[i] += (float)t[i];
  }
  float s = 0.f;
  #pragma unroll
  for (int i = 0; i < 8; ++i) s += v[i];
  #pragma unroll
  for (int m = 1; m < 64; m <<= 1) s += __shfl_xor(s, m, 64);
  float mean = s * (1.0f / 512.0f);
  float q = 0.f;
  #pragma unroll
  for (int i = 0; i < 8; ++i) { float d = v[i] - mean; q += d * d; }
  #pragma unroll
  for (int m = 1; m < 64; m <<= 1) q += __shfl_xor(q, m, 64);
  float rstd = rsqrtf(q * (1.0f / 512.0f) + 1e-5f);
  float4 g0 = *(const float4*)(gw + lane * 8), g1v = *(const float4*)(gw + lane * 8 + 4);
  float4 e0 = *(const float4*)(bw + lane * 8), e1 = *(const float4*)(bw + lane * 8 + 4);
  float gg[8] = {g0.x, g0.y, g0.z, g0.w, g1v.x, g1v.y, g1v.z, g1v.w};
  float bb[8] = {e0.x, e0.y, e0.z, e0.w, e1.x, e1.y, e1.z, e1.w};
  float o[8];
  #pragma unroll
  for (int i = 0; i < 8; ++i) o[i] = (v[i] - mean) * rstd * gg[i] + bb[i];
  if (outf) {
    float4 o0 = {o[0], o[1], o[2], o[3]}, o1 = {o[4], o[5], o[6], o[7]};
    *(float4*)(outf + off) = o0;
    *(float4*)(outf + off + 4) = o1;
  }
  if (outb) {
    bf16x8 ob;
    #pragma unroll
    for (int i = 0; i < 8; ++i) ob[i] = (bf16)o[i];
    *(bf16x8*)(outb + off) = ob;
  }
}

// ---------------- launch ----------------
extern "C" void kernel_launch(void* const* d_in, const int* in_sizes, int n_in,
                              void* d_out, int out_size, void* d_ws, size_t ws_size,
                              hipStream_t stream) {
  const float* x   = (const float*)d_in[0];
  const float* wq  = (const float*)d_in[2];
  const float* bq  = (const float*)d_in[3];
  const float* wk  = (const float*)d_in[4];
  const float* bk  = (const float*)d_in[5];
  const float* wv  = (const float*)d_in[6];
  const float* bv  = (const float*)d_in[7];
  const float* wo  = (const float*)d_in[8];
  const float* bo  = (const float*)d_in[9];
  const float* w1  = (const float*)d_in[10];
  const float* b1  = (const float*)d_in[11];
  const float* w2  = (const float*)d_in[12];
  const float* b2  = (const float*)d_in[13];
  const float* g1  = (const float*)d_in[14];
  const float* be1 = (const float*)d_in[15];
  const float* g2  = (const float*)d_in[16];
  const float* be2 = (const float*)d_in[17];
  float* out = (float*)d_out;

  prep_k<<<5126, 256, 0, stream>>>(x, wq, wk, wv, wo, w1, w2, bq, bk, bv);

  gemm8p_k<<<dim3(32, 6, 1), 512, 0, stream>>>(0, nullptr);    // QKV (V -> g_vT)
  attn_k<<<dim3(32, 32), 256, 0, stream>>>();                  // windowed attention
  gemm_k<<<dim3(64, 4, 2), 256, 0, stream>>>(bo);              // O-proj, split-K=2
  ln_k<<<2048, 256, 0, stream>>>(0, g1, be1, nullptr);         // LN1 -> x1b
  gemm8p_k<<<dim3(32, 8, 1), 512, 0, stream>>>(2, b1);         // FF1 + relu
  gemm8p_k<<<dim3(32, 2, 4), 512, 0, stream>>>(3, b2);         // FF2, split-K=4
  ln_k<<<2048, 256, 0, stream>>>(1, g2, be2, out);             // LN2 -> out
}

// Round 11
// 144.070 us; speedup vs baseline: 1.0865x; 1.0073x over previous
//
#include <hip/hip_runtime.h>

// ---------------- types ----------------
typedef __bf16 bf16;
typedef float  f32x4  __attribute__((ext_vector_type(4)));
typedef __bf16 bf16x8 __attribute__((ext_vector_type(8)));
typedef __bf16 bf16x4 __attribute__((ext_vector_type(4)));

#define GLOAD_LDS16(gsrc, ldst) \
  __builtin_amdgcn_global_load_lds((const __attribute__((address_space(1))) void*)(gsrc), \
                                   (__attribute__((address_space(3))) void*)(ldst), 16, 0, 0)

// ---------------- problem constants ----------------
constexpr int Bc   = 4;
constexpr int Tc   = 2048;
constexpr int Dc   = 512;
constexpr int Hc   = 8;
constexpr int DKc  = 64;
constexpr int DFFc = 2048;
constexpr int WINc = 128;
constexpr int Mr   = Bc * Tc;        // 8192 rows
constexpr size_t MD = (size_t)Mr * Dc;
constexpr int TVc  = 2176;           // padded t-stride of g_vT

// ---------------- device scratch (static, graph-capture safe) ----------------
__device__ bf16  g_xb[MD];                 // x cast to bf16
__device__ bf16  g_wqkvT[3 * Dc * Dc];     // [1536][512] = [wqT; wkT; wvT]
__device__ bf16  g_woT[Dc * Dc];           // [512][512]
__device__ bf16  g_w1T[DFFc * Dc];         // [2048][512]
__device__ bf16  g_w2T[Dc * DFFc];         // [512][2048]
__device__ float g_biasqkv[3 * Dc];
__device__ bf16  g_qkv[Mr * 3 * Dc];       // [8192][1536] : Q | K | (V region unused)
__device__ bf16  g_vT[(size_t)Bc * Hc * DKc * TVc];  // V^T [b][h][d][t]; t>=2048 tail stays 0
__device__ bf16  g_o[MD];                  // attention output, bf16
__device__ bf16  g_attnp[2 * MD];          // o @ wo partials (kz=0 has +bo), bf16
__device__ bf16  g_x1b[MD];                // LN1 out bf16
__device__ bf16  g_ff1[Mr * DFFc];         // relu(x1@w1+b1) bf16
__device__ bf16  g_ff2p[4 * MD];           // ff1@w2 partials (kz=0 has +b2), bf16

// ---------------- fused prep: x-cast + 6 weight transpose-casts + bias concat ----------------
__global__ __launch_bounds__(256) void prep_k(const float* __restrict__ x,
                                              const float* __restrict__ wq, const float* __restrict__ wk,
                                              const float* __restrict__ wv, const float* __restrict__ wo,
                                              const float* __restrict__ w1, const float* __restrict__ w2,
                                              const float* __restrict__ bq, const float* __restrict__ bk,
                                              const float* __restrict__ bv) {
  int bid = blockIdx.x;
  if (bid < 2048) {   // cast x
    size_t i = (size_t)bid * 2048 + threadIdx.x * 8;
    float4 a = *(const float4*)(x + i);
    float4 c = *(const float4*)(x + i + 4);
    bf16x8 o;
    o[0] = (bf16)a.x; o[1] = (bf16)a.y; o[2] = (bf16)a.z; o[3] = (bf16)a.w;
    o[4] = (bf16)c.x; o[5] = (bf16)c.y; o[6] = (bf16)c.z; o[7] = (bf16)c.w;
    *(bf16x8*)(g_xb + i) = o;
    return;
  }
  if (bid >= 5120) {  // bias concat
    int i = (bid - 5120) * 256 + threadIdx.x;
    if (i < 1536) g_biasqkv[i] = (i < 512) ? bq[i] : (i < 1024 ? bk[i - 512] : bv[i - 1024]);
    return;
  }
  const float* W; bf16* dst; int K, N, nx, ky;
  if (bid < 3072) {
    int local = bid - 2048;
    int wsel = local >> 8; local &= 255;
    nx = local & 15; ky = local >> 4; K = 512; N = 512;
    switch (wsel) {
      case 0: W = wq; dst = g_wqkvT;              break;
      case 1: W = wk; dst = g_wqkvT + 512 * 512;  break;
      case 2: W = wv; dst = g_wqkvT + 1024 * 512; break;
      default:W = wo; dst = g_woT;                break;
    }
  } else if (bid < 4096) {
    int local = bid - 3072;
    nx = local & 63; ky = local >> 6; K = 512; N = 2048; W = w1; dst = g_w1T;
  } else {
    int local = bid - 4096;
    nx = local & 15; ky = local >> 4; K = 2048; N = 512; W = w2; dst = g_w2T;
  }
  __shared__ float t[32][33];
  int n0 = nx * 32, k0 = ky * 32;
  int tx = threadIdx.x & 31, ty = threadIdx.x >> 5;
  #pragma unroll
  for (int i = 0; i < 4; ++i)
    t[ty + i * 8][tx] = W[(size_t)(k0 + ty + i * 8) * N + n0 + tx];
  __syncthreads();
  #pragma unroll
  for (int i = 0; i < 4; ++i)
    dst[(size_t)(n0 + ty + i * 8) * K + k0 + tx] = (bf16)t[tx][ty + i * 8];
}

// ============ 256x256 / BK=64 / 8-wave / 8-phase counted-vmcnt GEMM ============
// which: 0 = QKV (V -> g_vT transposed), 2 = FF1(relu), 3 = FF2 (split-K=4)
// T1 XCD swizzle: blocks sharing the A-panel (same bm) grouped on one XCD.
__global__ __launch_bounds__(512, 2) void gemm8p_k(int which, const float* __restrict__ bias_in) {
  // ---- XCD-chunked remap (gx = 32, nwg % 8 == 0 for all uses) ----
  const int h = blockIdx.x + 32 * (blockIdx.y + gridDim.y * blockIdx.z);
  const int xc = h & 7, hi = h >> 3;
  const int bm = xc + 8 * (hi & 3);          // gx/8 = 4 bm-values per XCD
  const int yz = hi >> 2;
  const int bn = yz % gridDim.y;
  const int kz = yz / gridDim.y;

  const bf16 *A, *BT; bf16* Cb; const float* bias;
  int N, K; bool relu = false;
  if (which == 0)      { A = g_xb;  BT = g_wqkvT; Cb = g_qkv; bias = g_biasqkv; N = 1536; K = 512; }
  else if (which == 2) { A = g_x1b; BT = g_w1T;   Cb = g_ff1; bias = bias_in;   N = 2048; K = 512; relu = true; }
  else                 { A = g_ff1; BT = g_w2T;   Cb = g_ff2p + (size_t)kz * MD; bias = bias_in; N = 512; K = 2048; }
  const float* bias0 = (kz == 0) ? bias : nullptr;
  const int kzoff = kz * 512;
  constexpr int NT = 8;                      // 512 / BK64

  __shared__ __align__(16) bf16 lds[65536];  // 128 KiB, 2 buffers x 64 KiB

  const int tid = threadIdx.x;
  const int w = tid >> 6, lane = tid & 63;
  const int wm = w >> 2, wn = w & 3;         // 2M x 4N waves; per-wave 128x64
  const int r = lane & 15, gg = lane >> 4;

  const bf16* gA0 = A  + (size_t)(bm * 256) * K + kzoff;
  const bf16* gB0 = BT + (size_t)(bn * 256) * K + kzoff;

  f32x4 acc[8][4] = {};

  auto stageHalf = [&](int S) {
    if (S >= 4 * NT) return;
    const int tau = S >> 2, hh = S & 3, buf = tau & 1;
    const int colT = tau * 64;
    if (hh >= 2) {                           // A K-half
      const int ks = hh - 2;
      char* dst = (char*)lds + buf * 65536 + ks * 16384 + w * 1024;
      #pragma unroll
      for (int swp = 0; swp < 2; ++swp) {
        int s = swp * 512 + tid;
        int row = s >> 2;
        int cb = (s & 3) ^ (((row >> 1) ^ (row >> 3)) & 3);
        GLOAD_LDS16(gA0 + (size_t)row * K + colT + ks * 32 + cb * 8, dst + swp * 8192);
      }
    } else {                                 // B M-half
      char* dst = (char*)lds + buf * 65536 + 32768 + hh * 16384 + w * 1024;
      #pragma unroll
      for (int swp = 0; swp < 2; ++swp) {
        int s = swp * 512 + tid;
        int row = hh * 128 + (s >> 3);
        int cb = (s & 7) ^ (row & 7);
        GLOAD_LDS16(gB0 + (size_t)row * K + colT + cb * 8, dst + swp * 8192);
      }
    }
  };

  #pragma unroll
  for (int S = 0; S < 7; ++S) stageHalf(S);
  asm volatile("s_waitcnt vmcnt(6)" ::: "memory");
  __builtin_amdgcn_s_barrier();

  #pragma unroll
  for (int t = 0; t < NT; ++t) {
    const bf16* lb = lds + (t & 1) * 32768;
    bf16x8 b0[4], b1[4], afr[4];

    // phase 0: all B frags + A(mi0-3, ks0); stage t+1 h3
    #pragma unroll
    for (int ni = 0; ni < 4; ++ni) {
      int row = wn * 64 + ni * 16 + r;
      b0[ni] = *(const bf16x8*)(lb + 16384 + row * 64 + ((gg ^ (r & 7)) << 3));
      b1[ni] = *(const bf16x8*)(lb + 16384 + row * 64 + (((4 + gg) ^ (r & 7)) << 3));
    }
    #pragma unroll
    for (int i = 0; i < 4; ++i) {
      int row = wm * 128 + i * 16 + r;
      afr[i] = *(const bf16x8*)(lb + row * 32 + ((gg ^ (((row >> 1) ^ (row >> 3)) & 3)) << 3));
    }
    asm volatile("" ::: "memory");
    stageHalf(4 * t + 7);
    __builtin_amdgcn_s_barrier();
    __builtin_amdgcn_s_setprio(1);
    #pragma unroll
    for (int i = 0; i < 4; ++i)
      #pragma unroll
      for (int ni = 0; ni < 4; ++ni)
        acc[i][ni] = __builtin_amdgcn_mfma_f32_16x16x32_bf16(afr[i], b0[ni], acc[i][ni], 0, 0, 0);
    __builtin_amdgcn_s_setprio(0);
    __builtin_amdgcn_s_barrier();

    // phase 1: A(mi4-7, ks0); stage t+2 h0
    #pragma unroll
    for (int i = 0; i < 4; ++i) {
      int row = wm * 128 + 64 + i * 16 + r;
      afr[i] = *(const bf16x8*)(lb + row * 32 + ((gg ^ (((row >> 1) ^ (row >> 3)) & 3)) << 3));
    }
    asm volatile("" ::: "memory");
    stageHalf(4 * t + 8);
    __builtin_amdgcn_s_barrier();
    __builtin_amdgcn_s_setprio(1);
    #pragma unroll
    for (int i = 0; i < 4; ++i)
      #pragma unroll
      for (int ni = 0; ni < 4; ++ni)
        acc[4 + i][ni] = __builtin_amdgcn_mfma_f32_16x16x32_bf16(afr[i], b0[ni], acc[4 + i][ni], 0, 0, 0);
    __builtin_amdgcn_s_setprio(0);
    __builtin_amdgcn_s_barrier();

    // phase 2: A(mi0-3, ks1); stage t+2 h1
    #pragma unroll
    for (int i = 0; i < 4; ++i) {
      int row = wm * 128 + i * 16 + r;
      afr[i] = *(const bf16x8*)(lb + 8192 + row * 32 + ((gg ^ (((row >> 1) ^ (row >> 3)) & 3)) << 3));
    }
    asm volatile("" ::: "memory");
    stageHalf(4 * t + 9);
    __builtin_amdgcn_s_barrier();
    __builtin_amdgcn_s_setprio(1);
    #pragma unroll
    for (int i = 0; i < 4; ++i)
      #pragma unroll
      for (int ni = 0; ni < 4; ++ni)
        acc[i][ni] = __builtin_amdgcn_mfma_f32_16x16x32_bf16(afr[i], b1[ni], acc[i][ni], 0, 0, 0);
    __builtin_amdgcn_s_setprio(0);
    __builtin_amdgcn_s_barrier();

    // phase 3: A(mi4-7, ks1); stage t+2 h2; GATE
    #pragma unroll
    for (int i = 0; i < 4; ++i) {
      int row = wm * 128 + 64 + i * 16 + r;
      afr[i] = *(const bf16x8*)(lb + 8192 + row * 32 + ((gg ^ (((row >> 1) ^ (row >> 3)) & 3)) << 3));
    }
    asm volatile("" ::: "memory");
    stageHalf(4 * t + 10);
    if (t < NT - 2)       asm volatile("s_waitcnt vmcnt(6)" ::: "memory");
    else if (t == NT - 2) asm volatile("s_waitcnt vmcnt(0)" ::: "memory");
    __builtin_amdgcn_s_barrier();
    __builtin_amdgcn_s_setprio(1);
    #pragma unroll
    for (int i = 0; i < 4; ++i)
      #pragma unroll
      for (int ni = 0; ni < 4; ++ni)
        acc[4 + i][ni] = __builtin_amdgcn_mfma_f32_16x16x32_bf16(afr[i], b1[ni], acc[4 + i][ni], 0, 0, 0);
    __builtin_amdgcn_s_setprio(0);
    __builtin_amdgcn_s_barrier();
  }

  // epilogue
  if (which == 0 && bn >= 4) {
    #pragma unroll
    for (int mi = 0; mi < 8; ++mi) {
      int row0 = bm * 256 + wm * 128 + mi * 16 + gg * 4;
      int bidx = row0 >> 11, t0 = row0 & 2047;
      #pragma unroll
      for (int ni = 0; ni < 4; ++ni) {
        int col = bn * 256 + wn * 64 + ni * 16 + r;   // in [1024,1536)
        float bv = bias[col];
        int vcol = col - 1024;
        bf16x4 ov;
        #pragma unroll
        for (int j = 0; j < 4; ++j) ov[j] = (bf16)(acc[mi][ni][j] + bv);
        *(bf16x4*)(g_vT + (size_t)(bidx * 512 + vcol) * TVc + t0) = ov;
      }
    }
    return;
  }
  #pragma unroll
  for (int mi = 0; mi < 8; ++mi) {
    int row0 = bm * 256 + wm * 128 + mi * 16 + gg * 4;
    #pragma unroll
    for (int ni = 0; ni < 4; ++ni) {
      int col = bn * 256 + wn * 64 + ni * 16 + r;
      float bv = bias0 ? bias0[col] : 0.f;
      #pragma unroll
      for (int j = 0; j < 4; ++j) {
        float v0 = acc[mi][ni][j] + bv;
        if (relu) v0 = fmaxf(v0, 0.f);
        Cb[(size_t)(row0 + j) * N + col] = (bf16)v0;
      }
    }
  }
}

// ---------------- legacy 128x128 GEMM (O-proj only), T1-swizzled ----------------
__global__ __launch_bounds__(256) void gemm_k(const float* __restrict__ bias_in) {
  // XCD remap: gx=64 -> 8 bm-values per XCD; grid (64,4,2), nwg=512
  const int h = blockIdx.x + 64 * (blockIdx.y + 4 * blockIdx.z);
  const int xc = h & 7, hi = h >> 3;
  const int bm = xc + 8 * (hi & 7);
  const int yz = hi >> 3;
  const int bn = yz & 3, kz = yz >> 2;

  const bf16* A = g_o; const bf16* BT = g_woT;
  bf16* Cb = g_attnp + (size_t)kz * MD;
  const float* bias = kz ? nullptr : bias_in;
  const int N = 512, K = 512, Klen = 256;

  __shared__ __align__(16) bf16 lA[128 * 32];
  __shared__ __align__(16) bf16 lB[128 * 32];
  int tid = threadIdx.x;
  int w = tid >> 6, lane = tid & 63;
  int wm = w >> 1, wn = w & 1;
  int r = lane & 15, gg = lane >> 4;

  f32x4 acc[4][4] = {};

  const bf16* gA = A + (size_t)(bm * 128 + (tid >> 2)) * K + (size_t)kz * Klen + (tid & 3) * 8;
  const bf16* gB = BT + (size_t)(bn * 128 + (tid >> 2)) * K + (size_t)kz * Klen + (tid & 3) * 8;
  char* lAb = (char*)lA + (tid & 0xC0) * 16;
  char* lBb = (char*)lB + (tid & 0xC0) * 16;

  for (int k0 = 0; k0 < Klen; k0 += 32) {
    GLOAD_LDS16(gA + k0,                  lAb);
    GLOAD_LDS16(gA + (size_t)64 * K + k0, lAb + 4096);
    GLOAD_LDS16(gB + k0,                  lBb);
    GLOAD_LDS16(gB + (size_t)64 * K + k0, lBb + 4096);
    asm volatile("s_waitcnt vmcnt(0)" ::: "memory");
    __syncthreads();
    bf16x8 afrag[4], bfrag[4];
    #pragma unroll
    for (int i = 0; i < 4; ++i)
      afrag[i] = *(const bf16x8*)(&lA[(wm * 64 + i * 16 + r) * 32 + gg * 8]);
    #pragma unroll
    for (int i = 0; i < 4; ++i)
      bfrag[i] = *(const bf16x8*)(&lB[(wn * 64 + i * 16 + r) * 32 + gg * 8]);
    #pragma unroll
    for (int mi = 0; mi < 4; ++mi)
      #pragma unroll
      for (int ni = 0; ni < 4; ++ni)
        acc[mi][ni] = __builtin_amdgcn_mfma_f32_16x16x32_bf16(afrag[mi], bfrag[ni], acc[mi][ni], 0, 0, 0);
    __syncthreads();
  }

  #pragma unroll
  for (int mi = 0; mi < 4; ++mi) {
    int row0 = bm * 128 + wm * 64 + mi * 16 + gg * 4;
    #pragma unroll
    for (int ni = 0; ni < 4; ++ni) {
      int col = bn * 128 + wn * 64 + ni * 16 + r;
      float bv = bias ? bias[col] : 0.f;
      #pragma unroll
      for (int j = 0; j < 4; ++j) {
        float v0 = acc[mi][ni][j] + bv;
        Cb[(size_t)(row0 + j) * N + col] = (bf16)v0;
      }
    }
  }
}

// ---------------- windowed attention: staged, counted-vmcnt, T1-swizzled ----------------
// Gate QK^T on K+Q only (vmcnt(6)); V's 6 DMAs land under QK^T+softmax and are
// drained by the pre-PV vmcnt(0). Raw barriers (waits derived; see comments).
__global__ __launch_bounds__(256) void attn_k() {
  constexpr int KT = 192;
  __shared__ __align__(16) bf16 lKP[KT * 64];  // K [key][8ch swz] -> reused as P [64][24ch swz]
  __shared__ __align__(16) bf16 lVT[64 * KT];  // V^T [d][24ch swz]
  int tid = threadIdx.x;
  // XCD remap: adjacent qt tiles (128-key overlap) grouped per XCD
  const int h = blockIdx.x + 32 * blockIdx.y;
  const int xc = h & 7, hi = h >> 3;
  const int qt = 4 * xc + (hi & 3);
  const int bh = hi >> 2;
  int b = bh >> 3, hd = bh & 7;
  int q0 = qt * 64;
  int w = tid >> 6, lane = tid & 63;
  int r = lane & 15, gg = lane >> 4;

  // (1) stage K: 6 DMAs
  {
    const bf16* kbase = g_qkv + (size_t)b * Tc * 1536 + 512 + hd * 64;
    char* ldst = (char*)lKP + w * 1024;
    #pragma unroll
    for (int p = 0; p < 6; ++p) {
      int s = p * 256 + tid;
      int key = s >> 3;
      int cb = (s & 7) ^ (key & 7);
      int gkey = q0 + key;
      int srow = gkey < Tc ? gkey : 0;
      GLOAD_LDS16(kbase + (size_t)srow * 1536 + cb * 8, ldst + p * 4096);
    }
  }
  // (2) Q fragment loads (pinned between K and V staging)
  __builtin_amdgcn_sched_barrier(0);
  bf16x8 qf0, qf1;
  {
    int qrow = q0 + w * 16 + r;
    const bf16* qp = g_qkv + (size_t)(b * Tc + qrow) * 1536 + hd * 64;
    qf0 = *(const bf16x8*)(qp + gg * 8);
    qf1 = *(const bf16x8*)(qp + 32 + gg * 8);
  }
  __builtin_amdgcn_sched_barrier(0);
  // (3) stage V^T: 6 DMAs (completion deferred to pre-PV gate)
  {
    const bf16* vbase = g_vT + (size_t)(bh * 64) * TVc + q0;
    char* ldst = (char*)lVT + w * 1024;
    #pragma unroll
    for (int p = 0; p < 6; ++p) {
      int s = p * 256 + tid;
      int d = s / 24;
      int sc = s - d * 24;
      int cb = sc ^ (d & 7);
      GLOAD_LDS16(vbase + (size_t)d * TVc + cb * 8, ldst + p * 4096);
    }
  }
  // gate: oldest 8 vmem (K6+Q2) retired; V's 6 may stay in flight
  asm volatile("s_waitcnt vmcnt(6)" ::: "memory");
  __builtin_amdgcn_s_barrier();

  // S = Q K^T (swizzled K reads)
  f32x4 s[12] = {};
  #pragma unroll
  for (int ni = 0; ni < 12; ++ni) {
    int key = ni * 16 + r;
    int sw = key & 7;
    bf16x8 k0f = *(const bf16x8*)(&lKP[key * 64 + ((gg ^ sw) << 3)]);
    bf16x8 k1f = *(const bf16x8*)(&lKP[key * 64 + (((4 | gg) ^ sw) << 3)]);
    s[ni] = __builtin_amdgcn_mfma_f32_16x16x32_bf16(qf0, k0f, s[ni], 0, 0, 0);
    s[ni] = __builtin_amdgcn_mfma_f32_16x16x32_bf16(qf1, k1f, s[ni], 0, 0, 0);
  }

  float mx[4] = {-3e38f, -3e38f, -3e38f, -3e38f};
  #pragma unroll
  for (int ni = 0; ni < 12; ++ni)
    #pragma unroll
    for (int j = 0; j < 4; ++j) {
      int qloc = w * 16 + gg * 4 + j;
      int col = ni * 16 + r;
      bool valid = (col >= qloc) && (col < qloc + WINc) && (q0 + col < Tc);
      float sv = valid ? s[ni][j] * 0.125f : -3e38f;
      s[ni][j] = sv;
      mx[j] = fmaxf(mx[j], sv);
    }
  #pragma unroll
  for (int m = 1; m < 16; m <<= 1)
    #pragma unroll
    for (int j = 0; j < 4; ++j) mx[j] = fmaxf(mx[j], __shfl_xor(mx[j], m, 64));

  float sm[4] = {0.f, 0.f, 0.f, 0.f};
  #pragma unroll
  for (int ni = 0; ni < 12; ++ni)
    #pragma unroll
    for (int j = 0; j < 4; ++j) {
      float p = __expf(s[ni][j] - mx[j]);
      s[ni][j] = p;
      sm[j] += p;
    }
  #pragma unroll
  for (int m = 1; m < 16; m <<= 1)
    #pragma unroll
    for (int j = 0; j < 4; ++j) sm[j] += __shfl_xor(sm[j], m, 64);

  // barrier #2: all waves' K-reads consumed (values used by MFMAs) -> lKP reusable
  __builtin_amdgcn_s_barrier();
  #pragma unroll
  for (int ni = 0; ni < 12; ++ni)
    #pragma unroll
    for (int j = 0; j < 4; ++j) {
      int q = w * 16 + gg * 4 + j;
      int col = ni * 16 + r;
      int idx = q * KT + ((((col >> 3) ^ (q & 7)) << 3) | (col & 7));
      lKP[idx] = (bf16)s[ni][j];
    }
  // gate: V DMAs landed (vmcnt) + own P writes committed (lgkm); then all-wave sync
  asm volatile("s_waitcnt vmcnt(0) lgkmcnt(0)" ::: "memory");
  __builtin_amdgcn_s_barrier();

  f32x4 o[4] = {};
  int swl = r & 7;
  #pragma unroll
  for (int ks = 0; ks < 6; ++ks) {
    int ch = ((ks * 4 + gg) ^ swl) << 3;
    bf16x8 pf = *(const bf16x8*)(&lKP[(w * 16 + r) * KT + ch]);
    #pragma unroll
    for (int nf = 0; nf < 4; ++nf) {
      bf16x8 vf = *(const bf16x8*)(&lVT[(nf * 16 + r) * KT + ch]);
      o[nf] = __builtin_amdgcn_mfma_f32_16x16x32_bf16(pf, vf, o[nf], 0, 0, 0);
    }
  }
  #pragma unroll
  for (int nf = 0; nf < 4; ++nf) {
    int dk = nf * 16 + r;
    #pragma unroll
    for (int j = 0; j < 4; ++j) {
      int qloc = w * 16 + gg * 4 + j;
      float ov = o[nf][j] / sm[j];
      g_o[(size_t)(b * Tc + q0 + qloc) * Dc + hd * 64 + dk] = (bf16)ov;
    }
  }
}

// ---------------- residual (bf16 base + np bf16 partials) + LayerNorm ----------------
__global__ __launch_bounds__(256) void ln_k(int which, const float* __restrict__ gw,
                                            const float* __restrict__ bw,
                                            float* __restrict__ outf_in) {
  int row = blockIdx.x * 4 + (threadIdx.x >> 6);
  int lane = threadIdx.x & 63;
  const bf16* a; const bf16* pb; int np; float* outf; bf16* outb;
  if (which == 0) { a = g_xb;  pb = g_attnp; np = 2; outf = nullptr;  outb = g_x1b; }
  else            { a = g_x1b; pb = g_ff2p;  np = 4; outf = outf_in;  outb = nullptr; }
  size_t off = (size_t)row * 512 + lane * 8;
  bf16x8 av = *(const bf16x8*)(a + off);
  float v[8];
  #pragma unroll
  for (int i = 0; i < 8; ++i) v[i] = (float)av[i];
  for (int p = 0; p < np; ++p) {
    bf16x8 t = *(const bf16x8*)(pb + (size_t)p * MD + off);
    #pragma unroll
    for (int i = 0; i < 8; ++i) v[i] += (float)t[i];
  }
  float s = 0.f;
  #pragma unroll
  for (int i = 0; i < 8; ++i) s += v[i];
  #pragma unroll
  for (int m = 1; m < 64; m <<= 1) s += __shfl_xor(s, m, 64);
  float mean = s * (1.0f / 512.0f);
  float q = 0.f;
  #pragma unroll
  for (int i = 0; i < 8; ++i) { float d = v[i] - mean; q += d * d; }
  #pragma unroll
  for (int m = 1; m < 64; m <<= 1) q += __shfl_xor(q, m, 64);
  float rstd = rsqrtf(q * (1.0f / 512.0f) + 1e-5f);
  float4 g0 = *(const float4*)(gw + lane * 8), g1v = *(const float4*)(gw + lane * 8 + 4);
  float4 e0 = *(const float4*)(bw + lane * 8), e1 = *(const float4*)(bw + lane * 8 + 4);
  float gg[8] = {g0.x, g0.y, g0.z, g0.w, g1v.x, g1v.y, g1v.z, g1v.w};
  float bb[8] = {e0.x, e0.y, e0.z, e0.w, e1.x, e1.y, e1.z, e1.w};
  float o[8];
  #pragma unroll
  for (int i = 0; i < 8; ++i) o[i] = (v[i] - mean) * rstd * gg[i] + bb[i];
  if (outf) {
    float4 o0 = {o[0], o[1], o[2], o[3]}, o1 = {o[4], o[5], o[6], o[7]};
    *(float4*)(outf + off) = o0;
    *(float4*)(outf + off + 4) = o1;
  }
  if (outb) {
    bf16x8 ob;
    #pragma unroll
    for (int i = 0; i < 8; ++i) ob[i] = (bf16)o[i];
    *(bf16x8*)(outb + off) = ob;
  }
}

// ---------------- launch ----------------
extern "C" void kernel_launch(void* const* d_in, const int* in_sizes, int n_in,
                              void* d_out, int out_size, void* d_ws, size_t ws_size,
                              hipStream_t stream) {
  const float* x   = (const float*)d_in[0];
  const float* wq  = (const float*)d_in[2];
  const float* bq  = (const float*)d_in[3];
  const float* wk  = (const float*)d_in[4];
  const float* bk  = (const float*)d_in[5];
  const float* wv  = (const float*)d_in[6];
  const float* bv  = (const float*)d_in[7];
  const float* wo  = (const float*)d_in[8];
  const float* bo  = (const float*)d_in[9];
  const float* w1  = (const float*)d_in[10];
  const float* b1  = (const float*)d_in[11];
  const float* w2  = (const float*)d_in[12];
  const float* b2  = (const float*)d_in[13];
  const float* g1  = (const float*)d_in[14];
  const float* be1 = (const float*)d_in[15];
  const float* g2  = (const float*)d_in[16];
  const float* be2 = (const float*)d_in[17];
  float* out = (float*)d_out;

  prep_k<<<5126, 256, 0, stream>>>(x, wq, wk, wv, wo, w1, w2, bq, bk, bv);

  gemm8p_k<<<dim3(32, 6, 1), 512, 0, stream>>>(0, nullptr);    // QKV (V -> g_vT)
  attn_k<<<dim3(32, 32), 256, 0, stream>>>();                  // windowed attention
  gemm_k<<<dim3(64, 4, 2), 256, 0, stream>>>(bo);              // O-proj, split-K=2
  ln_k<<<2048, 256, 0, stream>>>(0, g1, be1, nullptr);         // LN1 -> x1b
  gemm8p_k<<<dim3(32, 8, 1), 512, 0, stream>>>(2, b1);         // FF1 + relu
  gemm8p_k<<<dim3(32, 2, 4), 512, 0, stream>>>(3, b2);         // FF2, split-K=4
  ln_k<<<2048, 256, 0, stream>>>(1, g2, be2, out);             // LN2 -> out
}

// Round 12
// 143.364 us; speedup vs baseline: 1.0918x; 1.0049x over previous
//
#include <hip/hip_runtime.h>

// ---------------- types ----------------
typedef __bf16 bf16;
typedef float  f32x4  __attribute__((ext_vector_type(4)));
typedef __bf16 bf16x8 __attribute__((ext_vector_type(8)));
typedef __bf16 bf16x4 __attribute__((ext_vector_type(4)));

#define GLOAD_LDS16(gsrc, ldst) \
  __builtin_amdgcn_global_load_lds((const __attribute__((address_space(1))) void*)(gsrc), \
                                   (__attribute__((address_space(3))) void*)(ldst), 16, 0, 0)

// ---------------- problem constants ----------------
constexpr int Bc   = 4;
constexpr int Tc   = 2048;
constexpr int Dc   = 512;
constexpr int Hc   = 8;
constexpr int DKc  = 64;
constexpr int DFFc = 2048;
constexpr int WINc = 128;
constexpr int Mr   = Bc * Tc;        // 8192 rows
constexpr size_t MD = (size_t)Mr * Dc;
constexpr int TVc  = 2176;           // padded t-stride of g_vT

// ---------------- device scratch (static, graph-capture safe) ----------------
__device__ bf16  g_xb[MD];                 // x cast to bf16
__device__ bf16  g_wqkvT[3 * Dc * Dc];     // [1536][512] = [wqT; wkT; wvT]
__device__ bf16  g_woT[Dc * Dc];           // [512][512]
__device__ bf16  g_w1T[DFFc * Dc];         // [2048][512]
__device__ bf16  g_w2T[Dc * DFFc];         // [512][2048]
__device__ float g_biasqkv[3 * Dc];
__device__ bf16  g_qkv[Mr * 3 * Dc];       // [8192][1536] : Q | K | (V region unused)
__device__ bf16  g_vT[(size_t)Bc * Hc * DKc * TVc];  // V^T [b][h][d][t]; t>=2048 tail stays 0
__device__ bf16  g_o[MD];                  // attention output, bf16
__device__ bf16  g_attnp[2 * MD];          // o @ wo partials (kz=0 has +bo), bf16
__device__ bf16  g_x1b[MD];                // LN1 out bf16
__device__ bf16  g_ff1[Mr * DFFc];         // relu(x1@w1+b1) bf16
__device__ bf16  g_ff2p[4 * MD];           // ff1@w2 partials (kz=0 has +b2), bf16

// ---------------- fused prep: x-cast + 6 weight transpose-casts + bias concat ----------------
__global__ __launch_bounds__(256) void prep_k(const float* __restrict__ x,
                                              const float* __restrict__ wq, const float* __restrict__ wk,
                                              const float* __restrict__ wv, const float* __restrict__ wo,
                                              const float* __restrict__ w1, const float* __restrict__ w2,
                                              const float* __restrict__ bq, const float* __restrict__ bk,
                                              const float* __restrict__ bv) {
  int bid = blockIdx.x;
  if (bid < 2048) {   // cast x
    size_t i = (size_t)bid * 2048 + threadIdx.x * 8;
    float4 a = *(const float4*)(x + i);
    float4 c = *(const float4*)(x + i + 4);
    bf16x8 o;
    o[0] = (bf16)a.x; o[1] = (bf16)a.y; o[2] = (bf16)a.z; o[3] = (bf16)a.w;
    o[4] = (bf16)c.x; o[5] = (bf16)c.y; o[6] = (bf16)c.z; o[7] = (bf16)c.w;
    *(bf16x8*)(g_xb + i) = o;
    return;
  }
  if (bid >= 5120) {  // bias concat
    int i = (bid - 5120) * 256 + threadIdx.x;
    if (i < 1536) g_biasqkv[i] = (i < 512) ? bq[i] : (i < 1024 ? bk[i - 512] : bv[i - 1024]);
    return;
  }
  const float* W; bf16* dst; int K, N, nx, ky;
  if (bid < 3072) {
    int local = bid - 2048;
    int wsel = local >> 8; local &= 255;
    nx = local & 15; ky = local >> 4; K = 512; N = 512;
    switch (wsel) {
      case 0: W = wq; dst = g_wqkvT;              break;
      case 1: W = wk; dst = g_wqkvT + 512 * 512;  break;
      case 2: W = wv; dst = g_wqkvT + 1024 * 512; break;
      default:W = wo; dst = g_woT;                break;
    }
  } else if (bid < 4096) {
    int local = bid - 3072;
    nx = local & 63; ky = local >> 6; K = 512; N = 2048; W = w1; dst = g_w1T;
  } else {
    int local = bid - 4096;
    nx = local & 15; ky = local >> 4; K = 2048; N = 512; W = w2; dst = g_w2T;
  }
  __shared__ float t[32][33];
  int n0 = nx * 32, k0 = ky * 32;
  int tx = threadIdx.x & 31, ty = threadIdx.x >> 5;
  #pragma unroll
  for (int i = 0; i < 4; ++i)
    t[ty + i * 8][tx] = W[(size_t)(k0 + ty + i * 8) * N + n0 + tx];
  __syncthreads();
  // vectorized transposed store: thread -> (n_local, k-quad); bf16x4 per store
  int nl = threadIdx.x >> 3;        // 0..31
  int kq = threadIdx.x & 7;         // 0..7
  bf16x4 ov;
  #pragma unroll
  for (int d = 0; d < 4; ++d) ov[d] = (bf16)t[kq * 4 + d][nl];
  *(bf16x4*)(dst + (size_t)(n0 + nl) * K + k0 + kq * 4) = ov;
}

// ============ 256x256 / BK=64 / 8-wave / 8-phase counted-vmcnt GEMM ============
// which: 0 = QKV (V -> g_vT transposed), 2 = FF1(relu), 3 = FF2 (split-K=4)
// T1 XCD swizzle: blocks sharing the A-panel (same bm) grouped on one XCD.
__global__ __launch_bounds__(512, 2) void gemm8p_k(int which, const float* __restrict__ bias_in) {
  // ---- XCD-chunked remap (gx = 32, nwg % 8 == 0 for all uses) ----
  const int h = blockIdx.x + 32 * (blockIdx.y + gridDim.y * blockIdx.z);
  const int xc = h & 7, hi = h >> 3;
  const int bm = xc + 8 * (hi & 3);          // gx/8 = 4 bm-values per XCD
  const int yz = hi >> 2;
  const int bn = yz % gridDim.y;
  const int kz = yz / gridDim.y;

  const bf16 *A, *BT; bf16* Cb; const float* bias;
  int N, K; bool relu = false;
  if (which == 0)      { A = g_xb;  BT = g_wqkvT; Cb = g_qkv; bias = g_biasqkv; N = 1536; K = 512; }
  else if (which == 2) { A = g_x1b; BT = g_w1T;   Cb = g_ff1; bias = bias_in;   N = 2048; K = 512; relu = true; }
  else                 { A = g_ff1; BT = g_w2T;   Cb = g_ff2p + (size_t)kz * MD; bias = bias_in; N = 512; K = 2048; }
  const float* bias0 = (kz == 0) ? bias : nullptr;
  const int kzoff = kz * 512;
  constexpr int NT = 8;                      // 512 / BK64

  __shared__ __align__(16) bf16 lds[65536];  // 128 KiB, 2 buffers x 64 KiB

  const int tid = threadIdx.x;
  const int w = tid >> 6, lane = tid & 63;
  const int wm = w >> 2, wn = w & 3;         // 2M x 4N waves; per-wave 128x64
  const int r = lane & 15, gg = lane >> 4;

  const bf16* gA0 = A  + (size_t)(bm * 256) * K + kzoff;
  const bf16* gB0 = BT + (size_t)(bn * 256) * K + kzoff;

  f32x4 acc[8][4] = {};

  auto stageHalf = [&](int S) {
    if (S >= 4 * NT) return;
    const int tau = S >> 2, hh = S & 3, buf = tau & 1;
    const int colT = tau * 64;
    if (hh >= 2) {                           // A K-half
      const int ks = hh - 2;
      char* dst = (char*)lds + buf * 65536 + ks * 16384 + w * 1024;
      #pragma unroll
      for (int swp = 0; swp < 2; ++swp) {
        int s = swp * 512 + tid;
        int row = s >> 2;
        int cb = (s & 3) ^ (((row >> 1) ^ (row >> 3)) & 3);
        GLOAD_LDS16(gA0 + (size_t)row * K + colT + ks * 32 + cb * 8, dst + swp * 8192);
      }
    } else {                                 // B M-half
      char* dst = (char*)lds + buf * 65536 + 32768 + hh * 16384 + w * 1024;
      #pragma unroll
      for (int swp = 0; swp < 2; ++swp) {
        int s = swp * 512 + tid;
        int row = hh * 128 + (s >> 3);
        int cb = (s & 7) ^ (row & 7);
        GLOAD_LDS16(gB0 + (size_t)row * K + colT + cb * 8, dst + swp * 8192);
      }
    }
  };

  #pragma unroll
  for (int S = 0; S < 7; ++S) stageHalf(S);
  asm volatile("s_waitcnt vmcnt(6)" ::: "memory");
  __builtin_amdgcn_s_barrier();

  #pragma unroll
  for (int t = 0; t < NT; ++t) {
    const bf16* lb = lds + (t & 1) * 32768;
    bf16x8 b0[4], b1[4], afr[4];

    // phase 0: all B frags + A(mi0-3, ks0); stage t+1 h3
    #pragma unroll
    for (int ni = 0; ni < 4; ++ni) {
      int row = wn * 64 + ni * 16 + r;
      b0[ni] = *(const bf16x8*)(lb + 16384 + row * 64 + ((gg ^ (r & 7)) << 3));
      b1[ni] = *(const bf16x8*)(lb + 16384 + row * 64 + (((4 + gg) ^ (r & 7)) << 3));
    }
    #pragma unroll
    for (int i = 0; i < 4; ++i) {
      int row = wm * 128 + i * 16 + r;
      afr[i] = *(const bf16x8*)(lb + row * 32 + ((gg ^ (((row >> 1) ^ (row >> 3)) & 3)) << 3));
    }
    asm volatile("" ::: "memory");
    stageHalf(4 * t + 7);
    __builtin_amdgcn_s_barrier();
    __builtin_amdgcn_s_setprio(1);
    #pragma unroll
    for (int i = 0; i < 4; ++i)
      #pragma unroll
      for (int ni = 0; ni < 4; ++ni)
        acc[i][ni] = __builtin_amdgcn_mfma_f32_16x16x32_bf16(afr[i], b0[ni], acc[i][ni], 0, 0, 0);
    __builtin_amdgcn_s_setprio(0);
    __builtin_amdgcn_s_barrier();

    // phase 1: A(mi4-7, ks0); stage t+2 h0
    #pragma unroll
    for (int i = 0; i < 4; ++i) {
      int row = wm * 128 + 64 + i * 16 + r;
      afr[i] = *(const bf16x8*)(lb + row * 32 + ((gg ^ (((row >> 1) ^ (row >> 3)) & 3)) << 3));
    }
    asm volatile("" ::: "memory");
    stageHalf(4 * t + 8);
    __builtin_amdgcn_s_barrier();
    __builtin_amdgcn_s_setprio(1);
    #pragma unroll
    for (int i = 0; i < 4; ++i)
      #pragma unroll
      for (int ni = 0; ni < 4; ++ni)
        acc[4 + i][ni] = __builtin_amdgcn_mfma_f32_16x16x32_bf16(afr[i], b0[ni], acc[4 + i][ni], 0, 0, 0);
    __builtin_amdgcn_s_setprio(0);
    __builtin_amdgcn_s_barrier();

    // phase 2: A(mi0-3, ks1); stage t+2 h1
    #pragma unroll
    for (int i = 0; i < 4; ++i) {
      int row = wm * 128 + i * 16 + r;
      afr[i] = *(const bf16x8*)(lb + 8192 + row * 32 + ((gg ^ (((row >> 1) ^ (row >> 3)) & 3)) << 3));
    }
    asm volatile("" ::: "memory");
    stageHalf(4 * t + 9);
    __builtin_amdgcn_s_barrier();
    __builtin_amdgcn_s_setprio(1);
    #pragma unroll
    for (int i = 0; i < 4; ++i)
      #pragma unroll
      for (int ni = 0; ni < 4; ++ni)
        acc[i][ni] = __builtin_amdgcn_mfma_f32_16x16x32_bf16(afr[i], b1[ni], acc[i][ni], 0, 0, 0);
    __builtin_amdgcn_s_setprio(0);
    __builtin_amdgcn_s_barrier();

    // phase 3: A(mi4-7, ks1); stage t+2 h2; GATE
    #pragma unroll
    for (int i = 0; i < 4; ++i) {
      int row = wm * 128 + 64 + i * 16 + r;
      afr[i] = *(const bf16x8*)(lb + 8192 + row * 32 + ((gg ^ (((row >> 1) ^ (row >> 3)) & 3)) << 3));
    }
    asm volatile("" ::: "memory");
    stageHalf(4 * t + 10);
    if (t < NT - 2)       asm volatile("s_waitcnt vmcnt(6)" ::: "memory");
    else if (t == NT - 2) asm volatile("s_waitcnt vmcnt(0)" ::: "memory");
    __builtin_amdgcn_s_barrier();
    __builtin_amdgcn_s_setprio(1);
    #pragma unroll
    for (int i = 0; i < 4; ++i)
      #pragma unroll
      for (int ni = 0; ni < 4; ++ni)
        acc[4 + i][ni] = __builtin_amdgcn_mfma_f32_16x16x32_bf16(afr[i], b1[ni], acc[4 + i][ni], 0, 0, 0);
    __builtin_amdgcn_s_setprio(0);
    __builtin_amdgcn_s_barrier();
  }

  // epilogue
  if (which == 0 && bn >= 4) {
    #pragma unroll
    for (int mi = 0; mi < 8; ++mi) {
      int row0 = bm * 256 + wm * 128 + mi * 16 + gg * 4;
      int bidx = row0 >> 11, t0 = row0 & 2047;
      #pragma unroll
      for (int ni = 0; ni < 4; ++ni) {
        int col = bn * 256 + wn * 64 + ni * 16 + r;   // in [1024,1536)
        float bv = bias[col];
        int vcol = col - 1024;
        bf16x4 ov;
        #pragma unroll
        for (int j = 0; j < 4; ++j) ov[j] = (bf16)(acc[mi][ni][j] + bv);
        *(bf16x4*)(g_vT + (size_t)(bidx * 512 + vcol) * TVc + t0) = ov;
      }
    }
    return;
  }
  #pragma unroll
  for (int mi = 0; mi < 8; ++mi) {
    int row0 = bm * 256 + wm * 128 + mi * 16 + gg * 4;
    #pragma unroll
    for (int ni = 0; ni < 4; ++ni) {
      int col = bn * 256 + wn * 64 + ni * 16 + r;
      float bv = bias0 ? bias0[col] : 0.f;
      #pragma unroll
      for (int j = 0; j < 4; ++j) {
        float v0 = acc[mi][ni][j] + bv;
        if (relu) v0 = fmaxf(v0, 0.f);
        Cb[(size_t)(row0 + j) * N + col] = (bf16)v0;
      }
    }
  }
}

// ---------------- legacy 128x128 GEMM (O-proj only), T1-swizzled ----------------
__global__ __launch_bounds__(256) void gemm_k(const float* __restrict__ bias_in) {
  // XCD remap: gx=64 -> 8 bm-values per XCD; grid (64,4,2), nwg=512
  const int h = blockIdx.x + 64 * (blockIdx.y + 4 * blockIdx.z);
  const int xc = h & 7, hi = h >> 3;
  const int bm = xc + 8 * (hi & 7);
  const int yz = hi >> 3;
  const int bn = yz & 3, kz = yz >> 2;

  const bf16* A = g_o; const bf16* BT = g_woT;
  bf16* Cb = g_attnp + (size_t)kz * MD;
  const float* bias = kz ? nullptr : bias_in;
  const int N = 512, K = 512, Klen = 256;

  __shared__ __align__(16) bf16 lA[128 * 32];
  __shared__ __align__(16) bf16 lB[128 * 32];
  int tid = threadIdx.x;
  int w = tid >> 6, lane = tid & 63;
  int wm = w >> 1, wn = w & 1;
  int r = lane & 15, gg = lane >> 4;

  f32x4 acc[4][4] = {};

  const bf16* gA = A + (size_t)(bm * 128 + (tid >> 2)) * K + (size_t)kz * Klen + (tid & 3) * 8;
  const bf16* gB = BT + (size_t)(bn * 128 + (tid >> 2)) * K + (size_t)kz * Klen + (tid & 3) * 8;
  char* lAb = (char*)lA + (tid & 0xC0) * 16;
  char* lBb = (char*)lB + (tid & 0xC0) * 16;

  for (int k0 = 0; k0 < Klen; k0 += 32) {
    GLOAD_LDS16(gA + k0,                  lAb);
    GLOAD_LDS16(gA + (size_t)64 * K + k0, lAb + 4096);
    GLOAD_LDS16(gB + k0,                  lBb);
    GLOAD_LDS16(gB + (size_t)64 * K + k0, lBb + 4096);
    asm volatile("s_waitcnt vmcnt(0)" ::: "memory");
    __syncthreads();
    bf16x8 afrag[4], bfrag[4];
    #pragma unroll
    for (int i = 0; i < 4; ++i)
      afrag[i] = *(const bf16x8*)(&lA[(wm * 64 + i * 16 + r) * 32 + gg * 8]);
    #pragma unroll
    for (int i = 0; i < 4; ++i)
      bfrag[i] = *(const bf16x8*)(&lB[(wn * 64 + i * 16 + r) * 32 + gg * 8]);
    #pragma unroll
    for (int mi = 0; mi < 4; ++mi)
      #pragma unroll
      for (int ni = 0; ni < 4; ++ni)
        acc[mi][ni] = __builtin_amdgcn_mfma_f32_16x16x32_bf16(afrag[mi], bfrag[ni], acc[mi][ni], 0, 0, 0);
    __syncthreads();
  }

  #pragma unroll
  for (int mi = 0; mi < 4; ++mi) {
    int row0 = bm * 128 + wm * 64 + mi * 16 + gg * 4;
    #pragma unroll
    for (int ni = 0; ni < 4; ++ni) {
      int col = bn * 128 + wn * 64 + ni * 16 + r;
      float bv = bias ? bias[col] : 0.f;
      #pragma unroll
      for (int j = 0; j < 4; ++j) {
        float v0 = acc[mi][ni][j] + bv;
        Cb[(size_t)(row0 + j) * N + col] = (bf16)v0;
      }
    }
  }
}

// ---------------- windowed attention: staged, counted-vmcnt, T1-swizzled ----------------
// exp2-folded softmax: scale = 0.125*log2(e); rcp-based normalization.
__global__ __launch_bounds__(256) void attn_k() {
  constexpr int KT = 192;
  __shared__ __align__(16) bf16 lKP[KT * 64];  // K [key][8ch swz] -> reused as P [64][24ch swz]
  __shared__ __align__(16) bf16 lVT[64 * KT];  // V^T [d][24ch swz]
  int tid = threadIdx.x;
  // XCD remap: adjacent qt tiles (128-key overlap) grouped per XCD
  const int h = blockIdx.x + 32 * blockIdx.y;
  const int xc = h & 7, hi = h >> 3;
  const int qt = 4 * xc + (hi & 3);
  const int bh = hi >> 2;
  int b = bh >> 3, hd = bh & 7;
  int q0 = qt * 64;
  int w = tid >> 6, lane = tid & 63;
  int r = lane & 15, gg = lane >> 4;

  // (1) stage K: 6 DMAs
  {
    const bf16* kbase = g_qkv + (size_t)b * Tc * 1536 + 512 + hd * 64;
    char* ldst = (char*)lKP + w * 1024;
    #pragma unroll
    for (int p = 0; p < 6; ++p) {
      int s = p * 256 + tid;
      int key = s >> 3;
      int cb = (s & 7) ^ (key & 7);
      int gkey = q0 + key;
      int srow = gkey < Tc ? gkey : 0;
      GLOAD_LDS16(kbase + (size_t)srow * 1536 + cb * 8, ldst + p * 4096);
    }
  }
  // (2) Q fragment loads (pinned between K and V staging)
  __builtin_amdgcn_sched_barrier(0);
  bf16x8 qf0, qf1;
  {
    int qrow = q0 + w * 16 + r;
    const bf16* qp = g_qkv + (size_t)(b * Tc + qrow) * 1536 + hd * 64;
    qf0 = *(const bf16x8*)(qp + gg * 8);
    qf1 = *(const bf16x8*)(qp + 32 + gg * 8);
  }
  __builtin_amdgcn_sched_barrier(0);
  // (3) stage V^T: 6 DMAs (completion deferred to pre-PV gate)
  {
    const bf16* vbase = g_vT + (size_t)(bh * 64) * TVc + q0;
    char* ldst = (char*)lVT + w * 1024;
    #pragma unroll
    for (int p = 0; p < 6; ++p) {
      int s = p * 256 + tid;
      int d = s / 24;
      int sc = s - d * 24;
      int cb = sc ^ (d & 7);
      GLOAD_LDS16(vbase + (size_t)d * TVc + cb * 8, ldst + p * 4096);
    }
  }
  // gate: oldest 8 vmem (K6+Q2) retired; V's 6 may stay in flight
  asm volatile("s_waitcnt vmcnt(6)" ::: "memory");
  __builtin_amdgcn_s_barrier();

  // S = Q K^T (swizzled K reads)
  f32x4 s[12] = {};
  #pragma unroll
  for (int ni = 0; ni < 12; ++ni) {
    int key = ni * 16 + r;
    int sw = key & 7;
    bf16x8 k0f = *(const bf16x8*)(&lKP[key * 64 + ((gg ^ sw) << 3)]);
    bf16x8 k1f = *(const bf16x8*)(&lKP[key * 64 + (((4 | gg) ^ sw) << 3)]);
    s[ni] = __builtin_amdgcn_mfma_f32_16x16x32_bf16(qf0, k0f, s[ni], 0, 0, 0);
    s[ni] = __builtin_amdgcn_mfma_f32_16x16x32_bf16(qf1, k1f, s[ni], 0, 0, 0);
  }

  // mask + scale folded with log2(e): softmax via exp2 (identical result)
  const float SC2 = 0.125f * 1.4426950408889634f;
  float mx[4] = {-3e38f, -3e38f, -3e38f, -3e38f};
  #pragma unroll
  for (int ni = 0; ni < 12; ++ni)
    #pragma unroll
    for (int j = 0; j < 4; ++j) {
      int qloc = w * 16 + gg * 4 + j;
      int col = ni * 16 + r;
      bool valid = (col >= qloc) && (col < qloc + WINc) && (q0 + col < Tc);
      float sv = valid ? s[ni][j] * SC2 : -3e38f;
      s[ni][j] = sv;
      mx[j] = fmaxf(mx[j], sv);
    }
  #pragma unroll
  for (int m = 1; m < 16; m <<= 1)
    #pragma unroll
    for (int j = 0; j < 4; ++j) mx[j] = fmaxf(mx[j], __shfl_xor(mx[j], m, 64));

  float sm[4] = {0.f, 0.f, 0.f, 0.f};
  #pragma unroll
  for (int ni = 0; ni < 12; ++ni)
    #pragma unroll
    for (int j = 0; j < 4; ++j) {
      float p = exp2f(s[ni][j] - mx[j]);
      s[ni][j] = p;
      sm[j] += p;
    }
  #pragma unroll
  for (int m = 1; m < 16; m <<= 1)
    #pragma unroll
    for (int j = 0; j < 4; ++j) sm[j] += __shfl_xor(sm[j], m, 64);
  float rsm[4];
  #pragma unroll
  for (int j = 0; j < 4; ++j) rsm[j] = __builtin_amdgcn_rcpf(sm[j]);

  // barrier #2: all waves' K-reads consumed -> lKP reusable as P
  __builtin_amdgcn_s_barrier();
  #pragma unroll
  for (int ni = 0; ni < 12; ++ni)
    #pragma unroll
    for (int j = 0; j < 4; ++j) {
      int q = w * 16 + gg * 4 + j;
      int col = ni * 16 + r;
      int idx = q * KT + ((((col >> 3) ^ (q & 7)) << 3) | (col & 7));
      lKP[idx] = (bf16)s[ni][j];
    }
  // gate: V DMAs landed (vmcnt) + own P writes committed (lgkm); then all-wave sync
  asm volatile("s_waitcnt vmcnt(0) lgkmcnt(0)" ::: "memory");
  __builtin_amdgcn_s_barrier();

  f32x4 o[4] = {};
  int swl = r & 7;
  #pragma unroll
  for (int ks = 0; ks < 6; ++ks) {
    int ch = ((ks * 4 + gg) ^ swl) << 3;
    bf16x8 pf = *(const bf16x8*)(&lKP[(w * 16 + r) * KT + ch]);
    #pragma unroll
    for (int nf = 0; nf < 4; ++nf) {
      bf16x8 vf = *(const bf16x8*)(&lVT[(nf * 16 + r) * KT + ch]);
      o[nf] = __builtin_amdgcn_mfma_f32_16x16x32_bf16(pf, vf, o[nf], 0, 0, 0);
    }
  }
  #pragma unroll
  for (int nf = 0; nf < 4; ++nf) {
    int dk = nf * 16 + r;
    #pragma unroll
    for (int j = 0; j < 4; ++j) {
      int qloc = w * 16 + gg * 4 + j;
      float ov = o[nf][j] * rsm[j];
      g_o[(size_t)(b * Tc + q0 + qloc) * Dc + hd * 64 + dk] = (bf16)ov;
    }
  }
}

// ---------------- residual (bf16 base + np bf16 partials) + LayerNorm ----------------
__global__ __launch_bounds__(256) void ln_k(int which, const float* __restrict__ gw,
                                            const float* __restrict__ bw,
                                            float* __restrict__ outf_in) {
  int row = blockIdx.x * 4 + (threadIdx.x >> 6);
  int lane = threadIdx.x & 63;
  const bf16* a; const bf16* pb; int np; float* outf; bf16* outb;
  if (which == 0) { a = g_xb;  pb = g_attnp; np = 2; outf = nullptr;  outb = g_x1b; }
  else            { a = g_x1b; pb = g_ff2p;  np = 4; outf = outf_in;  outb = nullptr; }
  size_t off = (size_t)row * 512 + lane * 8;
  bf16x8 av = *(const bf16x8*)(a + off);
  float v[8];
  #pragma unroll
  for (int i = 0; i < 8; ++i) v[i] = (float)av[i];
  for (int p = 0; p < np; ++p) {
    bf16x8 t = *(const bf16x8*)(pb + (size_t)p * MD + off);
    #pragma unroll
    for (int i = 0; i < 8; ++i) v[i] += (float)t[i];
  }
  float s = 0.f;
  #pragma unroll
  for (int i = 0; i < 8; ++i) s += v[i];
  #pragma unroll
  for (int m = 1; m < 64; m <<= 1) s += __shfl_xor(s, m, 64);
  float mean = s * (1.0f / 512.0f);
  float q = 0.f;
  #pragma unroll
  for (int i = 0; i < 8; ++i) { float d = v[i] - mean; q += d * d; }
  #pragma unroll
  for (int m = 1; m < 64; m <<= 1) q += __shfl_xor(q, m, 64);
  float rstd = rsqrtf(q * (1.0f / 512.0f) + 1e-5f);
  float4 g0 = *(const float4*)(gw + lane * 8), g1v = *(const float4*)(gw + lane * 8 + 4);
  float4 e0 = *(const float4*)(bw + lane * 8), e1 = *(const float4*)(bw + lane * 8 + 4);
  float gg[8] = {g0.x, g0.y, g0.z, g0.w, g1v.x, g1v.y, g1v.z, g1v.w};
  float bb[8] = {e0.x, e0.y, e0.z, e0.w, e1.x, e1.y, e1.z, e1.w};
  float o[8];
  #pragma unroll
  for (int i = 0; i < 8; ++i) o[i] = (v[i] - mean) * rstd * gg[i] + bb[i];
  if (outf) {
    float4 o0 = {o[0], o[1], o[2], o[3]}, o1 = {o[4], o[5], o[6], o[7]};
    *(float4*)(outf + off) = o0;
    *(float4*)(outf + off + 4) = o1;
  }
  if (outb) {
    bf16x8 ob;
    #pragma unroll
    for (int i = 0; i < 8; ++i) ob[i] = (bf16)o[i];
    *(bf16x8*)(outb + off) = ob;
  }
}

// ---------------- launch ----------------
extern "C" void kernel_launch(void* const* d_in, const int* in_sizes, int n_in,
                              void* d_out, int out_size, void* d_ws, size_t ws_size,
                              hipStream_t stream) {
  const float* x   = (const float*)d_in[0];
  const float* wq  = (const float*)d_in[2];
  const float* bq  = (const float*)d_in[3];
  const float* wk  = (const float*)d_in[4];
  const float* bk  = (const float*)d_in[5];
  const float* wv  = (const float*)d_in[6];
  const float* bv  = (const float*)d_in[7];
  const float* wo  = (const float*)d_in[8];
  const float* bo  = (const float*)d_in[9];
  const float* w1  = (const float*)d_in[10];
  const float* b1  = (const float*)d_in[11];
  const float* w2  = (const float*)d_in[12];
  const float* b2  = (const float*)d_in[13];
  const float* g1  = (const float*)d_in[14];
  const float* be1 = (const float*)d_in[15];
  const float* g2  = (const float*)d_in[16];
  const float* be2 = (const float*)d_in[17];
  float* out = (float*)d_out;

  prep_k<<<5126, 256, 0, stream>>>(x, wq, wk, wv, wo, w1, w2, bq, bk, bv);

  gemm8p_k<<<dim3(32, 6, 1), 512, 0, stream>>>(0, nullptr);    // QKV (V -> g_vT)
  attn_k<<<dim3(32, 32), 256, 0, stream>>>();                  // windowed attention
  gemm_k<<<dim3(64, 4, 2), 256, 0, stream>>>(bo);              // O-proj, split-K=2
  ln_k<<<2048, 256, 0, stream>>>(0, g1, be1, nullptr);         // LN1 -> x1b
  gemm8p_k<<<dim3(32, 8, 1), 512, 0, stream>>>(2, b1);         // FF1 + relu
  gemm8p_k<<<dim3(32, 2, 4), 512, 0, stream>>>(3, b2);         // FF2, split-K=4
  ln_k<<<2048, 256, 0, stream>>>(1, g2, be2, out);             // LN2 -> out
}